// Round 3
// baseline (1158.127 us; speedup 1.0000x reference)
//
#include <hip/hip_runtime.h>

#define L_IMG 12
#define BATCH 64
#define NCLS  1000
#define DIM   512
#define NTM   96
#define SCALEF 0.044194173824159216f   // 1/sqrt(512)

typedef __attribute__((ext_vector_type(8))) short bf16x8;
typedef __attribute__((ext_vector_type(4))) float f32x4;

// ---------- bf16 helpers ----------
__device__ __forceinline__ float bf2f(unsigned short u) {
    return __uint_as_float(((unsigned int)u) << 16);
}
__device__ __forceinline__ unsigned short f2bf(float f) {
    unsigned int u = __float_as_uint(f);
    u += 0x7FFFu + ((u >> 16) & 1u);
    return (unsigned short)(u >> 16);
}
__device__ __forceinline__ void storeo(float* p, float v) { *p = v; }
__device__ __forceinline__ void storeo(unsigned short* p, float v) { *p = f2bf(v); }

// ---------- fp32 -> bf16 convert (n multiple of 4) ----------
__global__ __launch_bounds__(256)
void f2bf_kernel(const float* __restrict__ in, unsigned short* __restrict__ out, int n)
{
    int i = (blockIdx.x * 256 + threadIdx.x) * 4;
    if (i < n) {
        float4 v = *(const float4*)(in + i);
        ushort4 o;
        o.x = f2bf(v.x); o.y = f2bf(v.y); o.z = f2bf(v.z); o.w = f2bf(v.w);
        *(ushort4*)(out + i) = o;
    }
}

// ---------- Wvo[d,k] = sum_e cow[d,e]*cWv[e,k] (bf16 out), bvo[d] = sum_e cow[d,e]*cbv[e] ----------
__global__ __launch_bounds__(256)
void fold_wvo(const float* __restrict__ cow, const float* __restrict__ cWv,
              const float* __restrict__ cbv, unsigned short* __restrict__ Wvob,
              float* __restrict__ bvo)
{
    __shared__ float crow[DIM];
    __shared__ float red[256];
    const int d = blockIdx.x, t = threadIdx.x;
    float c0 = cow[d * DIM + t], c1 = cow[d * DIM + t + 256];
    crow[t] = c0; crow[t + 256] = c1;
    red[t] = c0 * cbv[t] + c1 * cbv[t + 256];
    __syncthreads();
    for (int s = 128; s > 0; s >>= 1) {
        if (t < s) red[t] += red[t + s];
        __syncthreads();
    }
    if (t == 0) bvo[d] = red[0];
    float a0 = 0.f, a1 = 0.f;
    for (int e = 0; e < DIM; e++) {
        float ce = crow[e];
        a0 += ce * cWv[e * DIM + t];
        a1 += ce * cWv[e * DIM + t + 256];
    }
    Wvob[d * DIM + t]       = f2bf(a0);
    Wvob[d * DIM + t + 256] = f2bf(a1);
}

// ---------- small fp32 tiled GEMM: C[M,N] = (A[M,K] @ W[N,K]^T + bias) * scale ----------
#define BKT 32
#define LDT 68
__global__ __launch_bounds__(256)
void gemm_bt_f32(const float* __restrict__ A, const float* __restrict__ W,
                 const float* __restrict__ bias, float* __restrict__ Co,
                 int M, int N, int K, float out_scale)
{
    __shared__ float As[BKT * LDT];
    __shared__ float Ws[BKT * LDT];
    const int tid = threadIdx.x;
    const int m0 = blockIdx.y << 6, n0 = blockIdx.x << 6;
    const int tx = tid & 15, ty = tid >> 4;
    float acc[4][4] = {};
    for (int k0 = 0; k0 < K; k0 += BKT) {
        #pragma unroll
        for (int i = 0; i < 2; i++) {
            int slot = tid + (i << 8);
            int r = slot >> 3, kq = slot & 7;
            float4 v = *(const float4*)(A + (size_t)(m0 + r) * K + k0 + (kq << 2));
            As[(kq*4+0)*LDT + r] = v.x; As[(kq*4+1)*LDT + r] = v.y;
            As[(kq*4+2)*LDT + r] = v.z; As[(kq*4+3)*LDT + r] = v.w;
            float4 w = *(const float4*)(W + (size_t)(n0 + r) * K + k0 + (kq << 2));
            Ws[(kq*4+0)*LDT + r] = w.x; Ws[(kq*4+1)*LDT + r] = w.y;
            Ws[(kq*4+2)*LDT + r] = w.z; Ws[(kq*4+3)*LDT + r] = w.w;
        }
        __syncthreads();
        #pragma unroll
        for (int kk = 0; kk < BKT; kk++) {
            float4 a = *(const float4*)(As + kk*LDT + ty*4);
            float4 w = *(const float4*)(Ws + kk*LDT + tx*4);
            acc[0][0] += a.x*w.x; acc[0][1] += a.x*w.y; acc[0][2] += a.x*w.z; acc[0][3] += a.x*w.w;
            acc[1][0] += a.y*w.x; acc[1][1] += a.y*w.y; acc[1][2] += a.y*w.z; acc[1][3] += a.y*w.w;
            acc[2][0] += a.z*w.x; acc[2][1] += a.z*w.y; acc[2][2] += a.z*w.z; acc[2][3] += a.z*w.w;
            acc[3][0] += a.w*w.x; acc[3][1] += a.w*w.y; acc[3][2] += a.w*w.z; acc[3][3] += a.w*w.w;
        }
        __syncthreads();
    }
    #pragma unroll
    for (int i = 0; i < 4; i++) {
        int mr = m0 + ty*4 + i;
        #pragma unroll
        for (int j = 0; j < 4; j++) {
            int n = n0 + tx*4 + j;
            float v = acc[i][j];
            if (bias) v += bias[n];
            Co[(size_t)mr * N + n] = v * out_scale;
        }
    }
}

// ---------- self-attention over the 12-layer axis, one block per batch ----------
__global__ __launch_bounds__(256)
void attn_kernel(const float* __restrict__ qkv, float* __restrict__ ao)
{
    __shared__ float lq[L_IMG * DIM];
    __shared__ float lk[L_IMG * DIM];
    __shared__ float sc[L_IMG * L_IMG];
    __shared__ float sa[L_IMG * L_IMG];
    const int b = blockIdx.x, tid = threadIdx.x;
    for (int i = 0; i < 6; i++) {
        int slot = tid + (i << 8);
        int l = slot >> 7, e4 = slot & 127;
        const float* row = qkv + (size_t)(l * BATCH + b) * 1536;
        *(float4*)(lq + l*DIM + e4*4) = *(const float4*)(row + e4*4);
        *(float4*)(lk + l*DIM + e4*4) = *(const float4*)(row + DIM + e4*4);
    }
    __syncthreads();
    if (tid < 144) {
        int l = tid / 12, m = tid % 12;
        float a = 0.f;
        for (int d4 = 0; d4 < 128; d4++) {
            float4 q = *(const float4*)(lq + l*DIM + d4*4);
            float4 k = *(const float4*)(lk + m*DIM + d4*4);
            a += q.x*k.x + q.y*k.y + q.z*k.z + q.w*k.w;
        }
        sc[tid] = a * SCALEF;
    }
    __syncthreads();
    if (tid < 12) {
        float mx = -1e30f;
        for (int m = 0; m < 12; m++) mx = fmaxf(mx, sc[tid*12 + m]);
        float e[12], s = 0.f;
        for (int m = 0; m < 12; m++) { e[m] = __expf(sc[tid*12 + m] - mx); s += e[m]; }
        float inv = 1.f / s;
        for (int m = 0; m < 12; m++) sa[tid*12 + m] = e[m] * inv;
    }
    __syncthreads();
    for (int i = 0; i < 2; i++) {
        int e = tid + (i << 8);
        float vv[12];
        #pragma unroll
        for (int m = 0; m < 12; m++)
            vv[m] = qkv[(size_t)(m * BATCH + b) * 1536 + 1024 + e];
        #pragma unroll
        for (int l = 0; l < 12; l++) {
            float a = 0.f;
            #pragma unroll
            for (int m = 0; m < 12; m++) a += sa[l*12 + m] * vv[m];
            ao[(size_t)(l * BATCH + b) * DIM + e] = a;
        }
    }
}

// ---------- normalize image features (xs layer 11) ----------
__global__ __launch_bounds__(256)
void img_kernel(const float* __restrict__ xs, float* __restrict__ imgn)
{
    __shared__ float red[256];
    const int b = blockIdx.x, tid = threadIdx.x;
    const float* row = xs + (size_t)(11 * BATCH + b) * DIM;
    float v0 = row[tid], v1 = row[tid + 256];
    red[tid] = v0*v0 + v1*v1;
    __syncthreads();
    for (int s = 128; s > 0; s >>= 1) {
        if (tid < s) red[tid] += red[tid + s];
        __syncthreads();
    }
    float inv = rsqrtf(red[0]);
    imgn[b*DIM + tid]       = v0 * inv;
    imgn[b*DIM + tid + 256] = v1 * inv;
}

// ---------- q2s fp32 [12,64,512] -> q2pb bf16 [64*16, 512], l>=12 zero ----------
__global__ __launch_bounds__(256)
void build_q2p(const float* __restrict__ q2s, unsigned short* __restrict__ q2pb)
{
    const int l = blockIdx.x, b = blockIdx.y, t = threadIdx.x;
    int d0 = t * 2;
    unsigned int o = 0;
    if (l < 12) {
        float2 v = *(const float2*)(q2s + (size_t)(l * BATCH + b) * DIM + d0);
        o = (unsigned int)f2bf(v.x) | ((unsigned int)f2bf(v.y) << 16);
    }
    ((unsigned int*)q2pb)[(size_t)(b * 16 + l) * 256 + t] = o;
}

// ---------- MFMA GEMM, zero-LDS: frags loaded direct from global (L2-served) ----------
// C[M,N] = A[M,K]@W[N,K]^T + bias, K = DIM = 512. 128x128 tile per block.
// Grid is 1-D; block ids are swizzled so the (N/128) n-tiles of one m-tile land
// on the SAME XCD (bids congruent mod 8) -> A-tile read once from HBM, then L2.
template<typename OutT>
__global__ __launch_bounds__(256, 4)
void gemm_mfma(const unsigned short* __restrict__ A, const unsigned short* __restrict__ W,
               const float* __restrict__ bias, OutT* __restrict__ Co,
               int M, int N, float scale)
{
    const int K = DIM;
    const int nbn = N >> 7;                 // n-tiles
    const int nbm = M >> 7;                 // m-tiles
    const int grp = nbn << 3;               // 8 m-tiles per group
    const int nfull = (nbm >> 3) << 3;
    const int bid = blockIdx.x;
    int mt, nt;
    if (bid < nfull * nbn) {
        int g = bid / grp, rr = bid - g * grp;
        mt = (g << 3) + (rr & 7);
        nt = rr >> 3;
    } else {
        int t2 = bid - nfull * nbn;
        mt = nfull + t2 / nbn;
        nt = t2 - (t2 / nbn) * nbn;
    }
    const int m0 = mt << 7, n0 = nt << 7;
    const int tid = threadIdx.x;
    const int w = tid >> 6, lane = tid & 63;
    const int mt0 = (w & 1) * 4, nt0 = (w >> 1) * 4;
    const int r16 = lane & 15, kq = lane >> 4;
    const unsigned short* pa = A + (size_t)(m0 + mt0*16 + r16) * K + (kq << 3);
    const unsigned short* pw = W + (size_t)(n0 + nt0*16 + r16) * K + (kq << 3);
    const size_t rstep = (size_t)16 * K;
    f32x4 acc[4][4] = {};

    #pragma unroll 2
    for (int k0 = 0; k0 < K; k0 += 32) {
        bf16x8 af[4], bf[4];
        #pragma unroll
        for (int i = 0; i < 4; i++) {
            af[i] = *(const bf16x8*)(pa + i * rstep + k0);
            bf[i] = *(const bf16x8*)(pw + i * rstep + k0);
        }
        #pragma unroll
        for (int i = 0; i < 4; i++)
            #pragma unroll
            for (int j = 0; j < 4; j++)
                acc[i][j] = __builtin_amdgcn_mfma_f32_16x16x32_bf16(af[i], bf[j], acc[i][j], 0, 0, 0);
    }
    const int rbase = (lane >> 4) * 4;
    #pragma unroll
    for (int i = 0; i < 4; i++)
        #pragma unroll
        for (int j = 0; j < 4; j++) {
            int gcol = n0 + (nt0 + j) * 16 + r16;
            float bv = bias ? bias[gcol] : 0.f;
            #pragma unroll
            for (int r = 0; r < 4; r++) {
                int grow = m0 + (mt0 + i) * 16 + rbase + r;
                storeo(Co + (size_t)grow * N + gcol, acc[i][j][r] * scale + bv);
            }
        }
}

// ---------- fused scores + softmax(m) + sum_l: one block = (class c, 8 batches) ----------
// A-frags loaded DIRECT from global (q2pb is 1 MB, L2-resident; frag = coalesced 16B/lane).
// K-tile staged in chunk-major LDS [chunk=kq][row] (16-B units): frag reads are
// 16-lane-contiguous (conflict-free), staging writes are 64-lane-contiguous.
// Double-buffered, one barrier/iter. Grid swizzled so the 8 bg-blocks of a class
// share an XCD (k2 class block fetched from HBM once, then L2-served).
// Softmax over m fully in registers (lane pair lane^8 holds complementary m parities);
// sum_l via shfl_xor(16/32) with row-group 3 (pad rows 12..15) masked.
__global__ __launch_bounds__(256, 4)
void fused_scores(const unsigned short* __restrict__ q2pb, const unsigned short* __restrict__ k2,
                  float* __restrict__ wout)
{
    __shared__ __align__(16) unsigned short KsBuf[2][384 * 8];   // 2 x 6144 B
    const int bid = blockIdx.x;
    const int g = bid >> 6, r = bid & 63;
    const int c = g * 8 + (r & 7), bg = r >> 3;
    const int tid = threadIdx.x;
    const int m0 = bg << 7;
    const int w = tid >> 6, lane = tid & 63;
    const int mt0 = w * 2;
    const int r16 = lane & 15, kq = lane >> 4;
    const size_t kb = (size_t)c * NTM * DIM;

    // staging map: unit u in [0,384): ch = u/96, row = u%96; LDS offset u*16 B
    const int u0 = tid, u1 = 256 + tid;
    const int ch0 = u0 / 96, row0 = u0 - ch0 * 96;
    const int ch1 = u1 / 96, row1 = u1 - ch1 * 96;
    const bool has1 = (tid < 128);
    const unsigned short* pk0 = k2 + kb + (size_t)row0 * DIM + (ch0 << 3);
    const unsigned short* pk1 = k2 + kb + (size_t)row1 * DIM + (ch1 << 3);

    // A-frag base: rows m0 + mt0*16 + r16 (+16 for second), col chunk kq
    const unsigned short* pa0 = q2pb + (size_t)(m0 + mt0 * 16 + r16) * DIM + (kq << 3);
    const unsigned short* pa1 = pa0 + 16 * DIM;

    f32x4 acc[2][6] = {};
    unsigned short* Kc = KsBuf[0];
    unsigned short* Kn = KsBuf[1];

    uint4 rk0 = *(const uint4*)pk0;
    uint4 rk1 = {0, 0, 0, 0};
    if (has1) rk1 = *(const uint4*)pk1;
    bf16x8 raf0 = *(const bf16x8*)pa0;
    bf16x8 raf1 = *(const bf16x8*)pa1;
    *(uint4*)(Kc + u0 * 8) = rk0;
    if (has1) *(uint4*)(Kc + u1 * 8) = rk1;
    __syncthreads();

    for (int t = 0; t < 16; t++) {
        bf16x8 af0 = raf0, af1 = raf1;
        if (t < 15) {
            const int ko = (t + 1) << 5;
            rk0 = *(const uint4*)(pk0 + ko);
            if (has1) rk1 = *(const uint4*)(pk1 + ko);
            raf0 = *(const bf16x8*)(pa0 + ko);
            raf1 = *(const bf16x8*)(pa1 + ko);
        }
        bf16x8 bfr[6];
        #pragma unroll
        for (int j = 0; j < 6; j++)
            bfr[j] = *(const bf16x8*)(Kc + ((kq * 96 + j * 16 + r16) << 3));
        #pragma unroll
        for (int j = 0; j < 6; j++) {
            acc[0][j] = __builtin_amdgcn_mfma_f32_16x16x32_bf16(af0, bfr[j], acc[0][j], 0, 0, 0);
            acc[1][j] = __builtin_amdgcn_mfma_f32_16x16x32_bf16(af1, bfr[j], acc[1][j], 0, 0, 0);
        }
        if (t < 15) {
            *(uint4*)(Kn + u0 * 8) = rk0;
            if (has1) *(uint4*)(Kn + u1 * 8) = rk1;
            __syncthreads();
            unsigned short* tmp = Kc; Kc = Kn; Kn = tmp;
        }
    }

    // in-register softmax over m (12 values per (row,t), split across lane pair lane^8)
    #pragma unroll
    for (int i = 0; i < 2; i++) {
        #pragma unroll
        for (int rr = 0; rr < 4; rr++) {
            float v0 = acc[i][0][rr], v1 = acc[i][1][rr], v2 = acc[i][2][rr];
            float v3 = acc[i][3][rr], v4 = acc[i][4][rr], v5 = acc[i][5][rr];
            float mx = fmaxf(fmaxf(fmaxf(v0, v1), fmaxf(v2, v3)), fmaxf(v4, v5));
            mx = fmaxf(mx, __shfl_xor(mx, 8, 64));
            float e0 = __expf(v0 - mx), e1 = __expf(v1 - mx), e2 = __expf(v2 - mx);
            float e3 = __expf(v3 - mx), e4 = __expf(v4 - mx), e5 = __expf(v5 - mx);
            float s = e0 + e1 + e2 + e3 + e4 + e5;
            s += __shfl_xor(s, 8, 64);
            float inv = 1.f / (96.f * s);
            acc[i][0][rr] = e0 * inv; acc[i][1][rr] = e1 * inv; acc[i][2][rr] = e2 * inv;
            acc[i][3][rr] = e3 * inv; acc[i][4][rr] = e4 * inv; acc[i][5][rr] = e5 * inv;
        }
    }

    // sum over l: in-lane over 4 rows (groups 0..2 = l 0..11; group 3 = pad),
    // then across row-groups via shfl_xor(16/32).
    const bool contrib = (lane >> 4) < 3;
    #pragma unroll
    for (int i = 0; i < 2; i++) {
        float s6[6];
        #pragma unroll
        for (int j = 0; j < 6; j++) {
            float t = contrib ? (acc[i][j][0] + acc[i][j][1] + acc[i][j][2] + acc[i][j][3]) : 0.f;
            t += __shfl_xor(t, 16, 64);
            t += __shfl_xor(t, 32, 64);
            s6[j] = t;
        }
        if (lane < 16) {
            const int b = bg * 8 + mt0 + i;
            float* dst = wout + ((size_t)(b * NCLS + c)) * NTM;
            #pragma unroll
            for (int j = 0; j < 6; j++)
                dst[j * 16 + r16] = s6[j];
        }
    }
}

// ---------- txt[b,c,:] = sum_tm w[b,c,tm] * v2p[c,tm,:] + cob ; block=(c, 16 batches) ----------
__global__ __launch_bounds__(256)
void txt_kernel(const float* __restrict__ wbuf, const unsigned short* __restrict__ v2p,
                const float* __restrict__ cob, unsigned short* __restrict__ txt)
{
    __shared__ float ws[16 * NTM];
    const int c = blockIdx.x, bg = blockIdx.y, tid = threadIdx.x;
    for (int idx = tid; idx < 16 * NTM; idx += 256) {
        int bl = idx / NTM, tm = idx - bl * NTM;
        ws[idx] = wbuf[((size_t)((bg * 16 + bl) * NCLS + c)) * NTM + tm];
    }
    __syncthreads();
    float a0[16] = {}, a1[16] = {};
    const unsigned int* vrow = (const unsigned int*)(v2p + (size_t)c * NTM * DIM) + tid;
    for (int tm = 0; tm < NTM; tm++) {
        unsigned int u = vrow[tm * 256];
        float vx = __uint_as_float(u << 16);
        float vy = __uint_as_float(u & 0xFFFF0000u);
        #pragma unroll
        for (int bl = 0; bl < 16; bl++) {
            float wv = ws[bl * NTM + tm];
            a0[bl] += wv * vx; a1[bl] += wv * vy;
        }
    }
    int d0 = tid * 2;
    float c0 = cob[d0], c1 = cob[d0 + 1];
    #pragma unroll
    for (int bl = 0; bl < 16; bl++) {
        int b = bg * 16 + bl;
        unsigned int o = (unsigned int)f2bf(a0[bl] + c0) | ((unsigned int)f2bf(a1[bl] + c1) << 16);
        ((unsigned int*)txt)[(size_t)(b * NCLS + c) * 256 + tid] = o;
    }
}

// ---------- n2[b,d] = sum_c txt[b,c,d]^2 ----------
__global__ __launch_bounds__(256)
void n2_kernel(const unsigned short* __restrict__ txt, float* __restrict__ n2)
{
    const int b = blockIdx.x, cg = blockIdx.y, t = threadIdx.x;
    float a0 = 0.f, a1 = 0.f;
    const unsigned int* p = (const unsigned int*)txt + ((size_t)(b * NCLS + cg * 250)) * 256 + t;
    for (int c = 0; c < 250; c++) {
        unsigned int u = p[c * 256];
        float vx = __uint_as_float(u << 16);
        float vy = __uint_as_float(u & 0xFFFF0000u);
        a0 += vx * vx; a1 += vy * vy;
    }
    atomicAdd(&n2[b * DIM + t * 2], a0);
    atomicAdd(&n2[b * DIM + t * 2 + 1], a1);
}

// ---------- u[b,d] = exp(ls) * img_n[b,d] / sqrt(n2[b,d]) ----------
__global__ __launch_bounds__(256)
void u_kernel(const float* __restrict__ imgn, const float* __restrict__ n2,
              const float* __restrict__ logit_scale, float* __restrict__ u)
{
    int i = blockIdx.x * 256 + threadIdx.x;
    float els = expf(logit_scale[0]);
    u[i] = els * imgn[i] * rsqrtf(n2[i]);
}

// ---------- logits[b,c] = sum_d u[b,d] * txt[b,c,d] ----------
__global__ __launch_bounds__(256)
void logits_kernel(const unsigned short* __restrict__ txt, const float* __restrict__ u,
                   float* __restrict__ out)
{
    __shared__ float lu[DIM];
    const int b = blockIdx.y, cg = blockIdx.x, tid = threadIdx.x;
    lu[tid]       = u[b*DIM + tid];
    lu[tid + 256] = u[b*DIM + tid + 256];
    __syncthreads();
    int wave = tid >> 6, lane = tid & 63;
    int c = (cg << 2) + wave;
    const unsigned short* row = txt + (size_t)(b * NCLS + c) * DIM;
    ushort4 p0 = ((const ushort4*)row)[lane*2];
    ushort4 p1 = ((const ushort4*)row)[lane*2 + 1];
    int d0 = lane * 8;
    float s = bf2f(p0.x)*lu[d0]   + bf2f(p0.y)*lu[d0+1] + bf2f(p0.z)*lu[d0+2] + bf2f(p0.w)*lu[d0+3]
            + bf2f(p1.x)*lu[d0+4] + bf2f(p1.y)*lu[d0+5] + bf2f(p1.z)*lu[d0+6] + bf2f(p1.w)*lu[d0+7];
    #pragma unroll
    for (int off = 32; off > 0; off >>= 1) s += __shfl_down(s, off, 64);
    if (lane == 0) out[b*NCLS + c] = s;
}

extern "C" void kernel_launch(void* const* d_in, const int* in_sizes, int n_in,
                              void* d_out, int out_size, void* d_ws, size_t ws_size,
                              hipStream_t stream)
{
    const float* x   = (const float*)d_in[0];
    const float* tfe = (const float*)d_in[1];
    const float* siw = (const float*)d_in[2];
    const float* sib = (const float*)d_in[3];
    const float* sow = (const float*)d_in[4];
    const float* sob = (const float*)d_in[5];
    const float* ciw = (const float*)d_in[6];
    const float* cib = (const float*)d_in[7];
    const float* cow = (const float*)d_in[8];
    const float* cob = (const float*)d_in[9];
    const float* ls  = (const float*)d_in[10];
    float* out = (float*)d_out;

    char* p = (char*)d_ws;
    auto alloc = [&](size_t bytes) { char* r = p; p += (bytes + 255) & ~255ull; return r; };
    unsigned short* tfeb = (unsigned short*)alloc((size_t)49152000 * 2);   // 98.3 MB
    unsigned short* k2   = (unsigned short*)alloc((size_t)96000 * DIM * 2);
    unsigned short* v2p  = (unsigned short*)alloc((size_t)96000 * DIM * 2);
    float* wbuf          = (float*)alloc((size_t)BATCH * NCLS * NTM * 4);  // 24.6 MB
    float* qkv           = (float*)alloc((size_t)768 * 1536 * 4);
    float* ao            = (float*)alloc((size_t)768 * DIM * 4);
    float* xs            = (float*)alloc((size_t)768 * DIM * 4);
    float* q2s           = (float*)alloc((size_t)768 * DIM * 4);
    unsigned short* q2pb = (unsigned short*)alloc((size_t)1024 * DIM * 2);
    unsigned short* cWkb = (unsigned short*)alloc((size_t)DIM * DIM * 2);
    unsigned short* Wvob = (unsigned short*)alloc((size_t)DIM * DIM * 2);
    float* bvo           = (float*)alloc(DIM * 4);
    float* n2            = (float*)alloc(BATCH * DIM * 4);
    float* uu            = (float*)alloc(BATCH * DIM * 4);
    float* imgn          = (float*)alloc(BATCH * DIM * 4);
    unsigned short* txt  = tfeb;   // alias: tfeb dead after v2p GEMM, txt written after

    hipMemsetAsync(n2, 0, BATCH * DIM * 4, stream);

    // weight/text prep
    f2bf_kernel<<<48000, 256, 0, stream>>>(tfe, tfeb, 49152000);
    f2bf_kernel<<<256, 256, 0, stream>>>(ciw + 512*512, cWkb, 262144);
    fold_wvo<<<512, 256, 0, stream>>>(cow, ciw + 1024*512, cib + 1024, Wvob, bvo);

    // self-attn head (fp32, small)
    gemm_bt_f32<<<dim3(24, 12), 256, 0, stream>>>(x, siw, sib, qkv, 768, 1536, 512, 1.f);
    attn_kernel<<<64, 256, 0, stream>>>(qkv, ao);
    gemm_bt_f32<<<dim3(8, 12), 256, 0, stream>>>(ao, sow, sob, xs, 768, 512, 512, 1.f);
    img_kernel<<<64, 256, 0, stream>>>(xs, imgn);
    gemm_bt_f32<<<dim3(8, 12), 256, 0, stream>>>(xs, ciw, cib, q2s, 768, 512, 512, SCALEF);
    build_q2p<<<dim3(16, 64), 256, 0, stream>>>(q2s, q2pb);

    // k2 / v2' projections (MFMA, zero-LDS, XCD-grouped swizzle)
    gemm_mfma<unsigned short><<<3000, 256, 0, stream>>>(
        tfeb, cWkb, cib + 512, k2, 96000, 512, 1.f);
    gemm_mfma<unsigned short><<<3000, 256, 0, stream>>>(
        tfeb, Wvob, bvo, v2p, 96000, 512, 1.f);

    // fused scores+softmax -> w[b,c,96]  (swizzled 1-D grid: 8 bg-blocks/class share an XCD)
    fused_scores<<<8000, 256, 0, stream>>>(q2pb, k2, wbuf);

    // txt = w @ v2' + cob  (bf16), then norms and logits
    txt_kernel<<<dim3(1000, 4), 256, 0, stream>>>(wbuf, v2p, cob, txt);
    n2_kernel<<<dim3(64, 4), 256, 0, stream>>>(txt, n2);
    u_kernel<<<128, 256, 0, stream>>>(imgn, n2, ls, uu);
    logits_kernel<<<dim3(250, 64), 256, 0, stream>>>(txt, uu, out);
}

// Round 4
// 973.898 us; speedup vs baseline: 1.1892x; 1.1892x over previous
//
#include <hip/hip_runtime.h>

#define L_IMG 12
#define BATCH 64
#define NCLS  1000
#define DIM   512
#define NTM   96
#define SCALEF 0.044194173824159216f   // 1/sqrt(512)

typedef __attribute__((ext_vector_type(8))) short bf16x8;
typedef __attribute__((ext_vector_type(4))) float f32x4;

// ---------- bf16 helpers ----------
__device__ __forceinline__ float bf2f(unsigned short u) {
    return __uint_as_float(((unsigned int)u) << 16);
}
__device__ __forceinline__ unsigned short f2bf(float f) {
    unsigned int u = __float_as_uint(f);
    u += 0x7FFFu + ((u >> 16) & 1u);
    return (unsigned short)(u >> 16);
}
__device__ __forceinline__ void storeo(float* p, float v) { *p = v; }
__device__ __forceinline__ void storeo(unsigned short* p, float v) { *p = f2bf(v); }

// XOR-swizzled LDS offset (shorts) for [row][32-short] tiles: 16B unit u ^= (row>>1)&3.
// Frag reads (16-lane phase, fixed kq, r16=0..15) and staging writes are uniform 2-way (free).
__device__ __forceinline__ int swz(int row, int u) {
    return (row << 5) + ((u ^ ((row >> 1) & 3)) << 3);
}

// ---------- fp32 -> bf16 convert (n multiple of 4) ----------
__global__ __launch_bounds__(256)
void f2bf_kernel(const float* __restrict__ in, unsigned short* __restrict__ out, int n)
{
    int i = (blockIdx.x * 256 + threadIdx.x) * 4;
    if (i < n) {
        float4 v = *(const float4*)(in + i);
        ushort4 o;
        o.x = f2bf(v.x); o.y = f2bf(v.y); o.z = f2bf(v.z); o.w = f2bf(v.w);
        *(ushort4*)(out + i) = o;
    }
}

// ---------- Wvo[d,k] = sum_e cow[d,e]*cWv[e,k] (bf16 out), bvo[d] = sum_e cow[d,e]*cbv[e] ----------
__global__ __launch_bounds__(256)
void fold_wvo(const float* __restrict__ cow, const float* __restrict__ cWv,
              const float* __restrict__ cbv, unsigned short* __restrict__ Wvob,
              float* __restrict__ bvo)
{
    __shared__ float crow[DIM];
    __shared__ float red[256];
    const int d = blockIdx.x, t = threadIdx.x;
    float c0 = cow[d * DIM + t], c1 = cow[d * DIM + t + 256];
    crow[t] = c0; crow[t + 256] = c1;
    red[t] = c0 * cbv[t] + c1 * cbv[t + 256];
    __syncthreads();
    for (int s = 128; s > 0; s >>= 1) {
        if (t < s) red[t] += red[t + s];
        __syncthreads();
    }
    if (t == 0) bvo[d] = red[0];
    float a0 = 0.f, a1 = 0.f;
    for (int e = 0; e < DIM; e++) {
        float ce = crow[e];
        a0 += ce * cWv[e * DIM + t];
        a1 += ce * cWv[e * DIM + t + 256];
    }
    Wvob[d * DIM + t]       = f2bf(a0);
    Wvob[d * DIM + t + 256] = f2bf(a1);
}

// ---------- small fp32 tiled GEMM: C[M,N] = (A[M,K] @ W[N,K]^T + bias) * scale ----------
#define BKT 32
#define LDT 68
__global__ __launch_bounds__(256)
void gemm_bt_f32(const float* __restrict__ A, const float* __restrict__ W,
                 const float* __restrict__ bias, float* __restrict__ Co,
                 int M, int N, int K, float out_scale)
{
    __shared__ float As[BKT * LDT];
    __shared__ float Ws[BKT * LDT];
    const int tid = threadIdx.x;
    const int m0 = blockIdx.y << 6, n0 = blockIdx.x << 6;
    const int tx = tid & 15, ty = tid >> 4;
    float acc[4][4] = {};
    for (int k0 = 0; k0 < K; k0 += BKT) {
        #pragma unroll
        for (int i = 0; i < 2; i++) {
            int slot = tid + (i << 8);
            int r = slot >> 3, kq = slot & 7;
            float4 v = *(const float4*)(A + (size_t)(m0 + r) * K + k0 + (kq << 2));
            As[(kq*4+0)*LDT + r] = v.x; As[(kq*4+1)*LDT + r] = v.y;
            As[(kq*4+2)*LDT + r] = v.z; As[(kq*4+3)*LDT + r] = v.w;
            float4 w = *(const float4*)(W + (size_t)(n0 + r) * K + k0 + (kq << 2));
            Ws[(kq*4+0)*LDT + r] = w.x; Ws[(kq*4+1)*LDT + r] = w.y;
            Ws[(kq*4+2)*LDT + r] = w.z; Ws[(kq*4+3)*LDT + r] = w.w;
        }
        __syncthreads();
        #pragma unroll
        for (int kk = 0; kk < BKT; kk++) {
            float4 a = *(const float4*)(As + kk*LDT + ty*4);
            float4 w = *(const float4*)(Ws + kk*LDT + tx*4);
            acc[0][0] += a.x*w.x; acc[0][1] += a.x*w.y; acc[0][2] += a.x*w.z; acc[0][3] += a.x*w.w;
            acc[1][0] += a.y*w.x; acc[1][1] += a.y*w.y; acc[1][2] += a.y*w.z; acc[1][3] += a.y*w.w;
            acc[2][0] += a.z*w.x; acc[2][1] += a.z*w.y; acc[2][2] += a.z*w.z; acc[2][3] += a.z*w.w;
            acc[3][0] += a.w*w.x; acc[3][1] += a.w*w.y; acc[3][2] += a.w*w.z; acc[3][3] += a.w*w.w;
        }
        __syncthreads();
    }
    #pragma unroll
    for (int i = 0; i < 4; i++) {
        int mr = m0 + ty*4 + i;
        #pragma unroll
        for (int j = 0; j < 4; j++) {
            int n = n0 + tx*4 + j;
            float v = acc[i][j];
            if (bias) v += bias[n];
            Co[(size_t)mr * N + n] = v * out_scale;
        }
    }
}

// ---------- self-attention over the 12-layer axis, one block per batch ----------
__global__ __launch_bounds__(256)
void attn_kernel(const float* __restrict__ qkv, float* __restrict__ ao)
{
    __shared__ float lq[L_IMG * DIM];
    __shared__ float lk[L_IMG * DIM];
    __shared__ float sc[L_IMG * L_IMG];
    __shared__ float sa[L_IMG * L_IMG];
    const int b = blockIdx.x, tid = threadIdx.x;
    for (int i = 0; i < 6; i++) {
        int slot = tid + (i << 8);
        int l = slot >> 7, e4 = slot & 127;
        const float* row = qkv + (size_t)(l * BATCH + b) * 1536;
        *(float4*)(lq + l*DIM + e4*4) = *(const float4*)(row + e4*4);
        *(float4*)(lk + l*DIM + e4*4) = *(const float4*)(row + DIM + e4*4);
    }
    __syncthreads();
    if (tid < 144) {
        int l = tid / 12, m = tid % 12;
        float a = 0.f;
        for (int d4 = 0; d4 < 128; d4++) {
            float4 q = *(const float4*)(lq + l*DIM + d4*4);
            float4 k = *(const float4*)(lk + m*DIM + d4*4);
            a += q.x*k.x + q.y*k.y + q.z*k.z + q.w*k.w;
        }
        sc[tid] = a * SCALEF;
    }
    __syncthreads();
    if (tid < 12) {
        float mx = -1e30f;
        for (int m = 0; m < 12; m++) mx = fmaxf(mx, sc[tid*12 + m]);
        float e[12], s = 0.f;
        for (int m = 0; m < 12; m++) { e[m] = __expf(sc[tid*12 + m] - mx); s += e[m]; }
        float inv = 1.f / s;
        for (int m = 0; m < 12; m++) sa[tid*12 + m] = e[m] * inv;
    }
    __syncthreads();
    for (int i = 0; i < 2; i++) {
        int e = tid + (i << 8);
        float vv[12];
        #pragma unroll
        for (int m = 0; m < 12; m++)
            vv[m] = qkv[(size_t)(m * BATCH + b) * 1536 + 1024 + e];
        #pragma unroll
        for (int l = 0; l < 12; l++) {
            float a = 0.f;
            #pragma unroll
            for (int m = 0; m < 12; m++) a += sa[l*12 + m] * vv[m];
            ao[(size_t)(l * BATCH + b) * DIM + e] = a;
        }
    }
}

// ---------- normalize image features (xs layer 11) ----------
__global__ __launch_bounds__(256)
void img_kernel(const float* __restrict__ xs, float* __restrict__ imgn)
{
    __shared__ float red[256];
    const int b = blockIdx.x, tid = threadIdx.x;
    const float* row = xs + (size_t)(11 * BATCH + b) * DIM;
    float v0 = row[tid], v1 = row[tid + 256];
    red[tid] = v0*v0 + v1*v1;
    __syncthreads();
    for (int s = 128; s > 0; s >>= 1) {
        if (tid < s) red[tid] += red[tid + s];
        __syncthreads();
    }
    float inv = rsqrtf(red[0]);
    imgn[b*DIM + tid]       = v0 * inv;
    imgn[b*DIM + tid + 256] = v1 * inv;
}

// ---------- q2s fp32 [12,64,512] -> q2pb bf16 [64*16, 512], l>=12 zero ----------
__global__ __launch_bounds__(256)
void build_q2p(const float* __restrict__ q2s, unsigned short* __restrict__ q2pb)
{
    const int l = blockIdx.x, b = blockIdx.y, t = threadIdx.x;
    int d0 = t * 2;
    unsigned int o = 0;
    if (l < 12) {
        float2 v = *(const float2*)(q2s + (size_t)(l * BATCH + b) * DIM + d0);
        o = (unsigned int)f2bf(v.x) | ((unsigned int)f2bf(v.y) << 16);
    }
    ((unsigned int*)q2pb)[(size_t)(b * 16 + l) * 256 + t] = o;
}

// ---------- MFMA GEMM: C[M,N] = A[M,K]@W[N,K]^T + bias ; 128x128 tile, BK=32 ----------
// Double-buffered LDS (reg-staged coalesced prefetch) with XOR-swizzled [row][32] tiles
// (2-way everywhere = free). 1-D grid swizzled so the N/128 n-tiles of one m-tile land
// on the same XCD (bids congruent mod 8): A-tile HBM-fetched once, then L2-served.
template<typename OutT>
__global__ __launch_bounds__(256, 4)
void gemm_mfma(const unsigned short* __restrict__ A, const unsigned short* __restrict__ W,
               const float* __restrict__ bias, OutT* __restrict__ Co,
               int M, int N, float scale)
{
    const int K = DIM;
    __shared__ __align__(16) unsigned short AsBuf[2][128 * 32];
    __shared__ __align__(16) unsigned short WsBuf[2][128 * 32];
    const int nbn = N >> 7, nbm = M >> 7;
    const int grp = nbn << 3;
    const int nfull = (nbm >> 3) << 3;
    const int bid = blockIdx.x;
    int mt, nt;
    if (bid < nfull * nbn) {
        int g = bid / grp, rr = bid - g * grp;
        mt = (g << 3) + (rr & 7);
        nt = rr >> 3;
    } else {
        int t2 = bid - nfull * nbn;
        mt = nfull + t2 / nbn;
        nt = t2 - (t2 / nbn) * nbn;
    }
    const int m0 = mt << 7, n0 = nt << 7;
    const int tid = threadIdx.x;
    const int w = tid >> 6, lane = tid & 63;
    const int mt0 = (w & 1) * 4, nt0 = (w >> 1) * 4;
    const int r16 = lane & 15, kq = lane >> 4;
    const int rs = tid >> 2, q = tid & 3, qs = q << 3;
    const unsigned short* pA0 = A + (size_t)(m0 + rs) * K + qs;
    const unsigned short* pA1 = pA0 + (size_t)64 * K;
    const unsigned short* pW0 = W + (size_t)(n0 + rs) * K + qs;
    const unsigned short* pW1 = pW0 + (size_t)64 * K;
    const int wo0 = swz(rs, q), wo1 = swz(64 + rs, q);
    int offa[4], offb[4];
    #pragma unroll
    for (int i = 0; i < 4; i++) {
        offa[i] = swz((mt0 + i) * 16 + r16, kq);
        offb[i] = swz((nt0 + i) * 16 + r16, kq);
    }
    f32x4 acc[4][4] = {};

    unsigned short* Ac = AsBuf[0]; unsigned short* An = AsBuf[1];
    unsigned short* Wc = WsBuf[0]; unsigned short* Wn = WsBuf[1];

    uint4 ta0 = *(const uint4*)pA0;
    uint4 ta1 = *(const uint4*)pA1;
    uint4 tw0 = *(const uint4*)pW0;
    uint4 tw1 = *(const uint4*)pW1;
    *(uint4*)(Ac + wo0) = ta0;
    *(uint4*)(Ac + wo1) = ta1;
    *(uint4*)(Wc + wo0) = tw0;
    *(uint4*)(Wc + wo1) = tw1;
    __syncthreads();

    const int ntk = K >> 5;
    for (int t = 0; t < ntk; t++) {
        if (t + 1 < ntk) {
            int ko = (t + 1) << 5;
            ta0 = *(const uint4*)(pA0 + ko);
            ta1 = *(const uint4*)(pA1 + ko);
            tw0 = *(const uint4*)(pW0 + ko);
            tw1 = *(const uint4*)(pW1 + ko);
        }
        bf16x8 af[4], bfr[4];
        #pragma unroll
        for (int i = 0; i < 4; i++) {
            af[i]  = *(const bf16x8*)(Ac + offa[i]);
            bfr[i] = *(const bf16x8*)(Wc + offb[i]);
        }
        __builtin_amdgcn_s_setprio(1);
        #pragma unroll
        for (int i = 0; i < 4; i++)
            #pragma unroll
            for (int j = 0; j < 4; j++)
                acc[i][j] = __builtin_amdgcn_mfma_f32_16x16x32_bf16(af[i], bfr[j], acc[i][j], 0, 0, 0);
        __builtin_amdgcn_s_setprio(0);
        if (t + 1 < ntk) {
            *(uint4*)(An + wo0) = ta0;
            *(uint4*)(An + wo1) = ta1;
            *(uint4*)(Wn + wo0) = tw0;
            *(uint4*)(Wn + wo1) = tw1;
            __syncthreads();
            unsigned short* tmp;
            tmp = Ac; Ac = An; An = tmp;
            tmp = Wc; Wc = Wn; Wn = tmp;
        }
    }
    const int rbase = (lane >> 4) * 4;
    #pragma unroll
    for (int i = 0; i < 4; i++)
        #pragma unroll
        for (int j = 0; j < 4; j++) {
            int gcol = n0 + (nt0 + j) * 16 + r16;
            float bv = bias ? bias[gcol] : 0.f;
            #pragma unroll
            for (int r = 0; r < 4; r++) {
                int grow = m0 + (mt0 + i) * 16 + rbase + r;
                storeo(Co + (size_t)grow * N + gcol, acc[i][j][r] * scale + bv);
            }
        }
}

// ---------- fused scores + softmax(m) + sum_l: one block = (class c, 8 batches) ----------
// Round-2 structure (coalesced reg-staged dbuf LDS for A and K) + XOR-swizzled tiles
// (conflict-free) + XCD-grouped 1-D grid (8 bg-blocks of a class share an XCD; k2 class
// block HBM-fetched once). Softmax over m fully in registers (lane pair lane^8 holds
// complementary m parities); sum_l via shfl_xor(16/32) with pad row-group 3 masked.
__global__ __launch_bounds__(256, 4)
void fused_scores(const unsigned short* __restrict__ q2pb, const unsigned short* __restrict__ k2,
                  float* __restrict__ wout)
{
    __shared__ __align__(16) unsigned short AsBuf[2][128 * 32];  // 2 x 8192 B
    __shared__ __align__(16) unsigned short KsBuf[2][96 * 32];   // 2 x 6144 B
    const int bid = blockIdx.x;
    const int g = bid >> 6, r = bid & 63;
    const int c = g * 8 + (r & 7), bg = r >> 3;
    const int tid = threadIdx.x;
    const int m0 = bg << 7;
    const int w = tid >> 6, lane = tid & 63;
    const int mt0 = w * 2;
    const int r16 = lane & 15, kq = lane >> 4;
    const size_t kb = (size_t)c * NTM * DIM;
    const int rs = tid >> 2, q = tid & 3, qs = q << 3;
    const unsigned short* pa0 = q2pb + (size_t)(m0 + rs) * DIM + qs;
    const unsigned short* pa1 = pa0 + (size_t)64 * DIM;
    const unsigned short* pk0 = k2 + kb + (size_t)rs * DIM + qs;
    const unsigned short* pk1 = pk0 + (size_t)64 * DIM;
    const bool half = (tid < 128);
    const int wo0 = swz(rs, q), wo1 = swz(64 + rs, q);
    int offa[2], offk[6];
    #pragma unroll
    for (int i = 0; i < 2; i++) offa[i] = swz((mt0 + i) * 16 + r16, kq);
    #pragma unroll
    for (int j = 0; j < 6; j++) offk[j] = swz(j * 16 + r16, kq);
    f32x4 acc[2][6] = {};

    unsigned short* Ac = AsBuf[0]; unsigned short* An = AsBuf[1];
    unsigned short* Kc = KsBuf[0]; unsigned short* Kn = KsBuf[1];

    uint4 ra0 = *(const uint4*)(pa0);
    uint4 ra1 = *(const uint4*)(pa1);
    uint4 rk0 = *(const uint4*)(pk0);
    uint4 rk1 = {0, 0, 0, 0};
    if (half) rk1 = *(const uint4*)(pk1);
    *(uint4*)(Ac + wo0) = ra0;
    *(uint4*)(Ac + wo1) = ra1;
    *(uint4*)(Kc + wo0) = rk0;
    if (half) *(uint4*)(Kc + wo1) = rk1;
    __syncthreads();

    for (int t = 0; t < 16; t++) {
        if (t < 15) {
            int ko = (t + 1) << 5;
            ra0 = *(const uint4*)(pa0 + ko);
            ra1 = *(const uint4*)(pa1 + ko);
            rk0 = *(const uint4*)(pk0 + ko);
            if (half) rk1 = *(const uint4*)(pk1 + ko);
        }
        bf16x8 af[2], bfr[6];
        #pragma unroll
        for (int i = 0; i < 2; i++)
            af[i] = *(const bf16x8*)(Ac + offa[i]);
        #pragma unroll
        for (int j = 0; j < 6; j++)
            bfr[j] = *(const bf16x8*)(Kc + offk[j]);
        __builtin_amdgcn_s_setprio(1);
        #pragma unroll
        for (int j = 0; j < 6; j++) {
            acc[0][j] = __builtin_amdgcn_mfma_f32_16x16x32_bf16(af[0], bfr[j], acc[0][j], 0, 0, 0);
            acc[1][j] = __builtin_amdgcn_mfma_f32_16x16x32_bf16(af[1], bfr[j], acc[1][j], 0, 0, 0);
        }
        __builtin_amdgcn_s_setprio(0);
        if (t < 15) {
            *(uint4*)(An + wo0) = ra0;
            *(uint4*)(An + wo1) = ra1;
            *(uint4*)(Kn + wo0) = rk0;
            if (half) *(uint4*)(Kn + wo1) = rk1;
            __syncthreads();
            unsigned short* tmp;
            tmp = Ac; Ac = An; An = tmp;
            tmp = Kc; Kc = Kn; Kn = tmp;
        }
    }

    // in-register softmax over m (12 values per (row,t), split across lane pair lane^8)
    #pragma unroll
    for (int i = 0; i < 2; i++) {
        #pragma unroll
        for (int rr = 0; rr < 4; rr++) {
            float v0 = acc[i][0][rr], v1 = acc[i][1][rr], v2 = acc[i][2][rr];
            float v3 = acc[i][3][rr], v4 = acc[i][4][rr], v5 = acc[i][5][rr];
            float mx = fmaxf(fmaxf(fmaxf(v0, v1), fmaxf(v2, v3)), fmaxf(v4, v5));
            mx = fmaxf(mx, __shfl_xor(mx, 8, 64));
            float e0 = __expf(v0 - mx), e1 = __expf(v1 - mx), e2 = __expf(v2 - mx);
            float e3 = __expf(v3 - mx), e4 = __expf(v4 - mx), e5 = __expf(v5 - mx);
            float s = e0 + e1 + e2 + e3 + e4 + e5;
            s += __shfl_xor(s, 8, 64);
            float inv = 1.f / (96.f * s);
            acc[i][0][rr] = e0 * inv; acc[i][1][rr] = e1 * inv; acc[i][2][rr] = e2 * inv;
            acc[i][3][rr] = e3 * inv; acc[i][4][rr] = e4 * inv; acc[i][5][rr] = e5 * inv;
        }
    }

    // sum over l: in-lane over 4 rows (groups 0..2 = l 0..11; group 3 = pad),
    // then across row-groups via shfl_xor(16/32).
    const bool contrib = (lane >> 4) < 3;
    #pragma unroll
    for (int i = 0; i < 2; i++) {
        float s6[6];
        #pragma unroll
        for (int j = 0; j < 6; j++) {
            float t = contrib ? (acc[i][j][0] + acc[i][j][1] + acc[i][j][2] + acc[i][j][3]) : 0.f;
            t += __shfl_xor(t, 16, 64);
            t += __shfl_xor(t, 32, 64);
            s6[j] = t;
        }
        if (lane < 16) {
            const int b = bg * 8 + mt0 + i;
            float* dst = wout + ((size_t)(b * NCLS + c)) * NTM;
            #pragma unroll
            for (int j = 0; j < 6; j++)
                dst[j * 16 + r16] = s6[j];
        }
    }
}

// ---------- txt[b,c,:] = sum_tm w[b,c,tm] * v2p[c,tm,:] + cob ; block=(c, 16 batches) ----------
__global__ __launch_bounds__(256)
void txt_kernel(const float* __restrict__ wbuf, const unsigned short* __restrict__ v2p,
                const float* __restrict__ cob, unsigned short* __restrict__ txt)
{
    __shared__ float ws[16 * NTM];
    const int c = blockIdx.x, bg = blockIdx.y, tid = threadIdx.x;
    for (int idx = tid; idx < 16 * NTM; idx += 256) {
        int bl = idx / NTM, tm = idx - bl * NTM;
        ws[idx] = wbuf[((size_t)((bg * 16 + bl) * NCLS + c)) * NTM + tm];
    }
    __syncthreads();
    float a0[16] = {}, a1[16] = {};
    const unsigned int* vrow = (const unsigned int*)(v2p + (size_t)c * NTM * DIM) + tid;
    for (int tm = 0; tm < NTM; tm++) {
        unsigned int u = vrow[tm * 256];
        float vx = __uint_as_float(u << 16);
        float vy = __uint_as_float(u & 0xFFFF0000u);
        #pragma unroll
        for (int bl = 0; bl < 16; bl++) {
            float wv = ws[bl * NTM + tm];
            a0[bl] += wv * vx; a1[bl] += wv * vy;
        }
    }
    int d0 = tid * 2;
    float c0 = cob[d0], c1 = cob[d0 + 1];
    #pragma unroll
    for (int bl = 0; bl < 16; bl++) {
        int b = bg * 16 + bl;
        unsigned int o = (unsigned int)f2bf(a0[bl] + c0) | ((unsigned int)f2bf(a1[bl] + c1) << 16);
        ((unsigned int*)txt)[(size_t)(b * NCLS + c) * 256 + tid] = o;
    }
}

// ---------- n2[b,d] = sum_c txt[b,c,d]^2 ----------
__global__ __launch_bounds__(256)
void n2_kernel(const unsigned short* __restrict__ txt, float* __restrict__ n2)
{
    const int b = blockIdx.x, cg = blockIdx.y, t = threadIdx.x;
    float a0 = 0.f, a1 = 0.f;
    const unsigned int* p = (const unsigned int*)txt + ((size_t)(b * NCLS + cg * 250)) * 256 + t;
    for (int c = 0; c < 250; c++) {
        unsigned int u = p[c * 256];
        float vx = __uint_as_float(u << 16);
        float vy = __uint_as_float(u & 0xFFFF0000u);
        a0 += vx * vx; a1 += vy * vy;
    }
    atomicAdd(&n2[b * DIM + t * 2], a0);
    atomicAdd(&n2[b * DIM + t * 2 + 1], a1);
}

// ---------- u[b,d] = exp(ls) * img_n[b,d] / sqrt(n2[b,d]) ----------
__global__ __launch_bounds__(256)
void u_kernel(const float* __restrict__ imgn, const float* __restrict__ n2,
              const float* __restrict__ logit_scale, float* __restrict__ u)
{
    int i = blockIdx.x * 256 + threadIdx.x;
    float els = expf(logit_scale[0]);
    u[i] = els * imgn[i] * rsqrtf(n2[i]);
}

// ---------- logits[b,c] = sum_d u[b,d] * txt[b,c,d] ----------
__global__ __launch_bounds__(256)
void logits_kernel(const unsigned short* __restrict__ txt, const float* __restrict__ u,
                   float* __restrict__ out)
{
    __shared__ float lu[DIM];
    const int b = blockIdx.y, cg = blockIdx.x, tid = threadIdx.x;
    lu[tid]       = u[b*DIM + tid];
    lu[tid + 256] = u[b*DIM + tid + 256];
    __syncthreads();
    int wave = tid >> 6, lane = tid & 63;
    int c = (cg << 2) + wave;
    const unsigned short* row = txt + (size_t)(b * NCLS + c) * DIM;
    ushort4 p0 = ((const ushort4*)row)[lane*2];
    ushort4 p1 = ((const ushort4*)row)[lane*2 + 1];
    int d0 = lane * 8;
    float s = bf2f(p0.x)*lu[d0]   + bf2f(p0.y)*lu[d0+1] + bf2f(p0.z)*lu[d0+2] + bf2f(p0.w)*lu[d0+3]
            + bf2f(p1.x)*lu[d0+4] + bf2f(p1.y)*lu[d0+5] + bf2f(p1.z)*lu[d0+6] + bf2f(p1.w)*lu[d0+7];
    #pragma unroll
    for (int off = 32; off > 0; off >>= 1) s += __shfl_down(s, off, 64);
    if (lane == 0) out[b*NCLS + c] = s;
}

extern "C" void kernel_launch(void* const* d_in, const int* in_sizes, int n_in,
                              void* d_out, int out_size, void* d_ws, size_t ws_size,
                              hipStream_t stream)
{
    const float* x   = (const float*)d_in[0];
    const float* tfe = (const float*)d_in[1];
    const float* siw = (const float*)d_in[2];
    const float* sib = (const float*)d_in[3];
    const float* sow = (const float*)d_in[4];
    const float* sob = (const float*)d_in[5];
    const float* ciw = (const float*)d_in[6];
    const float* cib = (const float*)d_in[7];
    const float* cow = (const float*)d_in[8];
    const float* cob = (const float*)d_in[9];
    const float* ls  = (const float*)d_in[10];
    float* out = (float*)d_out;

    char* p = (char*)d_ws;
    auto alloc = [&](size_t bytes) { char* r = p; p += (bytes + 255) & ~255ull; return r; };
    unsigned short* tfeb = (unsigned short*)alloc((size_t)49152000 * 2);   // 98.3 MB
    unsigned short* k2   = (unsigned short*)alloc((size_t)96000 * DIM * 2);
    unsigned short* v2p  = (unsigned short*)alloc((size_t)96000 * DIM * 2);
    float* wbuf          = (float*)alloc((size_t)BATCH * NCLS * NTM * 4);  // 24.6 MB
    float* qkv           = (float*)alloc((size_t)768 * 1536 * 4);
    float* ao            = (float*)alloc((size_t)768 * DIM * 4);
    float* xs            = (float*)alloc((size_t)768 * DIM * 4);
    float* q2s           = (float*)alloc((size_t)768 * DIM * 4);
    unsigned short* q2pb = (unsigned short*)alloc((size_t)1024 * DIM * 2);
    unsigned short* cWkb = (unsigned short*)alloc((size_t)DIM * DIM * 2);
    unsigned short* Wvob = (unsigned short*)alloc((size_t)DIM * DIM * 2);
    float* bvo           = (float*)alloc(DIM * 4);
    float* n2            = (float*)alloc(BATCH * DIM * 4);
    float* uu            = (float*)alloc(BATCH * DIM * 4);
    float* imgn          = (float*)alloc(BATCH * DIM * 4);
    unsigned short* txt  = tfeb;   // alias: tfeb dead after v2p GEMM, txt written after

    hipMemsetAsync(n2, 0, BATCH * DIM * 4, stream);

    // weight/text prep
    f2bf_kernel<<<48000, 256, 0, stream>>>(tfe, tfeb, 49152000);
    f2bf_kernel<<<256, 256, 0, stream>>>(ciw + 512*512, cWkb, 262144);
    fold_wvo<<<512, 256, 0, stream>>>(cow, ciw + 1024*512, cib + 1024, Wvob, bvo);

    // self-attn head (fp32, small)
    gemm_bt_f32<<<dim3(24, 12), 256, 0, stream>>>(x, siw, sib, qkv, 768, 1536, 512, 1.f);
    attn_kernel<<<64, 256, 0, stream>>>(qkv, ao);
    gemm_bt_f32<<<dim3(8, 12), 256, 0, stream>>>(ao, sow, sob, xs, 768, 512, 512, 1.f);
    img_kernel<<<64, 256, 0, stream>>>(xs, imgn);
    gemm_bt_f32<<<dim3(8, 12), 256, 0, stream>>>(xs, ciw, cib, q2s, 768, 512, 512, SCALEF);
    build_q2p<<<dim3(16, 64), 256, 0, stream>>>(q2s, q2pb);

    // k2 / v2' projections (MFMA, dbuf LDS, XCD-grouped 1-D grid)
    gemm_mfma<unsigned short><<<3000, 256, 0, stream>>>(
        tfeb, cWkb, cib + 512, k2, 96000, 512, 1.f);
    gemm_mfma<unsigned short><<<3000, 256, 0, stream>>>(
        tfeb, Wvob, bvo, v2p, 96000, 512, 1.f);

    // fused scores+softmax -> w[b,c,96]  (XCD-grouped 1-D grid)
    fused_scores<<<8000, 256, 0, stream>>>(q2pb, k2, wbuf);

    // txt = w @ v2' + cob  (bf16), then norms and logits
    txt_kernel<<<dim3(1000, 4), 256, 0, stream>>>(wbuf, v2p, cob, txt);
    n2_kernel<<<dim3(64, 4), 256, 0, stream>>>(txt, n2);
    u_kernel<<<128, 256, 0, stream>>>(imgn, n2, ls, uu);
    logits_kernel<<<dim3(250, 64), 256, 0, stream>>>(txt, uu, out);
}

// Round 5
// 896.954 us; speedup vs baseline: 1.2912x; 1.0858x over previous
//
#include <hip/hip_runtime.h>

#define L_IMG 12
#define BATCH 64
#define NCLS  1000
#define DIM   512
#define NTM   96
#define SCALEF 0.044194173824159216f   // 1/sqrt(512)

typedef __attribute__((ext_vector_type(8))) short bf16x8;
typedef __attribute__((ext_vector_type(4))) float f32x4;

// ---------- bf16 helpers ----------
__device__ __forceinline__ float bf2f(unsigned short u) {
    return __uint_as_float(((unsigned int)u) << 16);
}
__device__ __forceinline__ unsigned short f2bf(float f) {
    unsigned int u = __float_as_uint(f);
    u += 0x7FFFu + ((u >> 16) & 1u);
    return (unsigned short)(u >> 16);
}
__device__ __forceinline__ void storeo(float* p, float v) { *p = v; }
__device__ __forceinline__ void storeo(unsigned short* p, float v) { *p = f2bf(v); }

// XOR-swizzled LDS offset (shorts) for [row][32-short] tiles: 16B unit u ^= (row>>1)&3.
// ds_read frags (16-lane phase, fixed kq) are uniform 2-way (free).
__device__ __forceinline__ int swz(int row, int u) {
    return (row << 5) + ((u ^ ((row >> 1) & 3)) << 3);
}

// async global->LDS, 16 B per lane; LDS dest = wave-uniform base + lane*16 (linear).
// Swizzle achieved by inverse-permuting the per-lane GLOBAL source (rule #21).
__device__ __forceinline__ void gload16(const unsigned short* g, unsigned short* l) {
    __builtin_amdgcn_global_load_lds(
        (const __attribute__((address_space(1))) void*)g,
        (__attribute__((address_space(3))) void*)l, 16, 0, 0);
}

// ---------- fp32 -> bf16 convert (n multiple of 4) ----------
__global__ __launch_bounds__(256)
void f2bf_kernel(const float* __restrict__ in, unsigned short* __restrict__ out, int n)
{
    int i = (blockIdx.x * 256 + threadIdx.x) * 4;
    if (i < n) {
        float4 v = *(const float4*)(in + i);
        ushort4 o;
        o.x = f2bf(v.x); o.y = f2bf(v.y); o.z = f2bf(v.z); o.w = f2bf(v.w);
        *(ushort4*)(out + i) = o;
    }
}

// ---------- Wvo[d,k] = sum_e cow[d,e]*cWv[e,k] (bf16 out), bvo[d] = sum_e cow[d,e]*cbv[e] ----------
__global__ __launch_bounds__(256)
void fold_wvo(const float* __restrict__ cow, const float* __restrict__ cWv,
              const float* __restrict__ cbv, unsigned short* __restrict__ Wvob,
              float* __restrict__ bvo)
{
    __shared__ float crow[DIM];
    __shared__ float red[256];
    const int d = blockIdx.x, t = threadIdx.x;
    float c0 = cow[d * DIM + t], c1 = cow[d * DIM + t + 256];
    crow[t] = c0; crow[t + 256] = c1;
    red[t] = c0 * cbv[t] + c1 * cbv[t + 256];
    __syncthreads();
    for (int s = 128; s > 0; s >>= 1) {
        if (t < s) red[t] += red[t + s];
        __syncthreads();
    }
    if (t == 0) bvo[d] = red[0];
    float a0 = 0.f, a1 = 0.f;
    for (int e = 0; e < DIM; e++) {
        float ce = crow[e];
        a0 += ce * cWv[e * DIM + t];
        a1 += ce * cWv[e * DIM + t + 256];
    }
    Wvob[d * DIM + t]       = f2bf(a0);
    Wvob[d * DIM + t + 256] = f2bf(a1);
}

// ---------- small fp32 tiled GEMM: C[M,N] = (A[M,K] @ W[N,K]^T + bias) * scale ----------
#define BKT 32
#define LDT 68
__global__ __launch_bounds__(256)
void gemm_bt_f32(const float* __restrict__ A, const float* __restrict__ W,
                 const float* __restrict__ bias, float* __restrict__ Co,
                 int M, int N, int K, float out_scale)
{
    __shared__ float As[BKT * LDT];
    __shared__ float Ws[BKT * LDT];
    const int tid = threadIdx.x;
    const int m0 = blockIdx.y << 6, n0 = blockIdx.x << 6;
    const int tx = tid & 15, ty = tid >> 4;
    float acc[4][4] = {};
    for (int k0 = 0; k0 < K; k0 += BKT) {
        #pragma unroll
        for (int i = 0; i < 2; i++) {
            int slot = tid + (i << 8);
            int r = slot >> 3, kq = slot & 7;
            float4 v = *(const float4*)(A + (size_t)(m0 + r) * K + k0 + (kq << 2));
            As[(kq*4+0)*LDT + r] = v.x; As[(kq*4+1)*LDT + r] = v.y;
            As[(kq*4+2)*LDT + r] = v.z; As[(kq*4+3)*LDT + r] = v.w;
            float4 w = *(const float4*)(W + (size_t)(n0 + r) * K + k0 + (kq << 2));
            Ws[(kq*4+0)*LDT + r] = w.x; Ws[(kq*4+1)*LDT + r] = w.y;
            Ws[(kq*4+2)*LDT + r] = w.z; Ws[(kq*4+3)*LDT + r] = w.w;
        }
        __syncthreads();
        #pragma unroll
        for (int kk = 0; kk < BKT; kk++) {
            float4 a = *(const float4*)(As + kk*LDT + ty*4);
            float4 w = *(const float4*)(Ws + kk*LDT + tx*4);
            acc[0][0] += a.x*w.x; acc[0][1] += a.x*w.y; acc[0][2] += a.x*w.z; acc[0][3] += a.x*w.w;
            acc[1][0] += a.y*w.x; acc[1][1] += a.y*w.y; acc[1][2] += a.y*w.z; acc[1][3] += a.y*w.w;
            acc[2][0] += a.z*w.x; acc[2][1] += a.z*w.y; acc[2][2] += a.z*w.z; acc[2][3] += a.z*w.w;
            acc[3][0] += a.w*w.x; acc[3][1] += a.w*w.y; acc[3][2] += a.w*w.z; acc[3][3] += a.w*w.w;
        }
        __syncthreads();
    }
    #pragma unroll
    for (int i = 0; i < 4; i++) {
        int mr = m0 + ty*4 + i;
        #pragma unroll
        for (int j = 0; j < 4; j++) {
            int n = n0 + tx*4 + j;
            float v = acc[i][j];
            if (bias) v += bias[n];
            Co[(size_t)mr * N + n] = v * out_scale;
        }
    }
}

// ---------- self-attention over the 12-layer axis, one block per batch ----------
__global__ __launch_bounds__(256)
void attn_kernel(const float* __restrict__ qkv, float* __restrict__ ao)
{
    __shared__ float lq[L_IMG * DIM];
    __shared__ float lk[L_IMG * DIM];
    __shared__ float sc[L_IMG * L_IMG];
    __shared__ float sa[L_IMG * L_IMG];
    const int b = blockIdx.x, tid = threadIdx.x;
    for (int i = 0; i < 6; i++) {
        int slot = tid + (i << 8);
        int l = slot >> 7, e4 = slot & 127;
        const float* row = qkv + (size_t)(l * BATCH + b) * 1536;
        *(float4*)(lq + l*DIM + e4*4) = *(const float4*)(row + e4*4);
        *(float4*)(lk + l*DIM + e4*4) = *(const float4*)(row + DIM + e4*4);
    }
    __syncthreads();
    if (tid < 144) {
        int l = tid / 12, m = tid % 12;
        float a = 0.f;
        for (int d4 = 0; d4 < 128; d4++) {
            float4 q = *(const float4*)(lq + l*DIM + d4*4);
            float4 k = *(const float4*)(lk + m*DIM + d4*4);
            a += q.x*k.x + q.y*k.y + q.z*k.z + q.w*k.w;
        }
        sc[tid] = a * SCALEF;
    }
    __syncthreads();
    if (tid < 12) {
        float mx = -1e30f;
        for (int m = 0; m < 12; m++) mx = fmaxf(mx, sc[tid*12 + m]);
        float e[12], s = 0.f;
        for (int m = 0; m < 12; m++) { e[m] = __expf(sc[tid*12 + m] - mx); s += e[m]; }
        float inv = 1.f / s;
        for (int m = 0; m < 12; m++) sa[tid*12 + m] = e[m] * inv;
    }
    __syncthreads();
    for (int i = 0; i < 2; i++) {
        int e = tid + (i << 8);
        float vv[12];
        #pragma unroll
        for (int m = 0; m < 12; m++)
            vv[m] = qkv[(size_t)(m * BATCH + b) * 1536 + 1024 + e];
        #pragma unroll
        for (int l = 0; l < 12; l++) {
            float a = 0.f;
            #pragma unroll
            for (int m = 0; m < 12; m++) a += sa[l*12 + m] * vv[m];
            ao[(size_t)(l * BATCH + b) * DIM + e] = a;
        }
    }
}

// ---------- normalize image features (xs layer 11) ----------
__global__ __launch_bounds__(256)
void img_kernel(const float* __restrict__ xs, float* __restrict__ imgn)
{
    __shared__ float red[256];
    const int b = blockIdx.x, tid = threadIdx.x;
    const float* row = xs + (size_t)(11 * BATCH + b) * DIM;
    float v0 = row[tid], v1 = row[tid + 256];
    red[tid] = v0*v0 + v1*v1;
    __syncthreads();
    for (int s = 128; s > 0; s >>= 1) {
        if (tid < s) red[tid] += red[tid + s];
        __syncthreads();
    }
    float inv = rsqrtf(red[0]);
    imgn[b*DIM + tid]       = v0 * inv;
    imgn[b*DIM + tid + 256] = v1 * inv;
}

// ---------- q2s fp32 [12,64,512] -> q2pb bf16 [64*16, 512], l>=12 zero ----------
__global__ __launch_bounds__(256)
void build_q2p(const float* __restrict__ q2s, unsigned short* __restrict__ q2pb)
{
    const int l = blockIdx.x, b = blockIdx.y, t = threadIdx.x;
    int d0 = t * 2;
    unsigned int o = 0;
    if (l < 12) {
        float2 v = *(const float2*)(q2s + (size_t)(l * BATCH + b) * DIM + d0);
        o = (unsigned int)f2bf(v.x) | ((unsigned int)f2bf(v.y) << 16);
    }
    ((unsigned int*)q2pb)[(size_t)(b * 16 + l) * 256 + t] = o;
}

// ---------- MFMA GEMM: C[M,N] = A[M,K]@W[N,K]^T + bias ; 128x128 tile, BK=32 ----------
// Staging via async global_load_lds width=16: linear LDS dest, inverse-swizzled
// per-lane global source, swizzled ds_read (involution => same placement as R4).
// Double-buffered, one barrier/iter; loads issued before the MFMA cluster.
template<typename OutT>
__global__ __launch_bounds__(256, 4)
void gemm_mfma(const unsigned short* __restrict__ A, const unsigned short* __restrict__ W,
               const float* __restrict__ bias, OutT* __restrict__ Co,
               int M, int N, float scale)
{
    const int K = DIM;
    __shared__ __align__(16) unsigned short AsBuf[2][128 * 32];
    __shared__ __align__(16) unsigned short WsBuf[2][128 * 32];
    const int m0 = blockIdx.y << 7, n0 = blockIdx.x << 7;
    const int tid = threadIdx.x;
    const int w = tid >> 6, lane = tid & 63;
    const int mt0 = (w & 1) * 4, nt0 = (w >> 1) * 4;
    const int r16 = lane & 15, kq = lane >> 4;
    // staging: wave w stages rows 32w..32w+31 of A and of W (2 async instrs each)
    const int row0 = (w << 5) + (lane >> 2), row1 = row0 + 16;
    const int sc0 = ((lane & 3) ^ ((row0 >> 1) & 3)) << 3;   // inverse-swizzled col chunk
    const int sc1 = ((lane & 3) ^ ((row1 >> 1) & 3)) << 3;
    const unsigned short* gA0 = A + (size_t)(m0 + row0) * K + sc0;
    const unsigned short* gA1 = A + (size_t)(m0 + row1) * K + sc1;
    const unsigned short* gW0 = W + (size_t)(n0 + row0) * K + sc0;
    const unsigned short* gW1 = W + (size_t)(n0 + row1) * K + sc1;
    const int lw = w << 10;   // wave-uniform LDS base (shorts): 32 rows * 32
    int offa[4], offb[4];
    #pragma unroll
    for (int i = 0; i < 4; i++) {
        offa[i] = swz((mt0 + i) * 16 + r16, kq);
        offb[i] = swz((nt0 + i) * 16 + r16, kq);
    }
    f32x4 acc[4][4] = {};

    gload16(gA0, AsBuf[0] + lw);
    gload16(gA1, AsBuf[0] + lw + 512);
    gload16(gW0, WsBuf[0] + lw);
    gload16(gW1, WsBuf[0] + lw + 512);
    __syncthreads();

    #pragma unroll
    for (int t = 0; t < 16; t++) {
        const int cur = t & 1, nxt = cur ^ 1;
        if (t < 15) {
            const int ko = (t + 1) << 5;
            gload16(gA0 + ko, AsBuf[nxt] + lw);
            gload16(gA1 + ko, AsBuf[nxt] + lw + 512);
            gload16(gW0 + ko, WsBuf[nxt] + lw);
            gload16(gW1 + ko, WsBuf[nxt] + lw + 512);
        }
        bf16x8 af[4], bfr[4];
        #pragma unroll
        for (int i = 0; i < 4; i++) {
            af[i]  = *(const bf16x8*)(AsBuf[cur] + offa[i]);
            bfr[i] = *(const bf16x8*)(WsBuf[cur] + offb[i]);
        }
        #pragma unroll
        for (int i = 0; i < 4; i++)
            #pragma unroll
            for (int j = 0; j < 4; j++)
                acc[i][j] = __builtin_amdgcn_mfma_f32_16x16x32_bf16(af[i], bfr[j], acc[i][j], 0, 0, 0);
        if (t < 15) __syncthreads();
    }
    const int rbase = (lane >> 4) * 4;
    #pragma unroll
    for (int i = 0; i < 4; i++)
        #pragma unroll
        for (int j = 0; j < 4; j++) {
            int gcol = n0 + (nt0 + j) * 16 + r16;
            float bv = bias ? bias[gcol] : 0.f;
            #pragma unroll
            for (int r = 0; r < 4; r++) {
                int grow = m0 + (mt0 + i) * 16 + rbase + r;
                storeo(Co + (size_t)grow * N + gcol, acc[i][j][r] * scale + bv);
            }
        }
}

// ---------- fused scores + softmax(m) + sum_l: one block = (class c, 8 batches) ----------
// Same async global_load_lds staging (A: 4 waves x 32 rows; K: waves 0-2 x 32 rows).
// XCD-grouped 1-D grid (8 bg-blocks of a class share an XCD; FETCH ~52 MB proven).
// Softmax over m fully in registers; sum_l via shfl_xor(16/32), pad row-group masked.
__global__ __launch_bounds__(256, 4)
void fused_scores(const unsigned short* __restrict__ q2pb, const unsigned short* __restrict__ k2,
                  float* __restrict__ wout)
{
    __shared__ __align__(16) unsigned short AsBuf[2][128 * 32];  // 2 x 8192 B
    __shared__ __align__(16) unsigned short KsBuf[2][96 * 32];   // 2 x 6144 B
    const int bid = blockIdx.x;
    const int g = bid >> 6, r = bid & 63;
    const int c = g * 8 + (r & 7), bg = r >> 3;
    const int tid = threadIdx.x;
    const int m0 = bg << 7;
    const int w = tid >> 6, lane = tid & 63;
    const int mt0 = w * 2;
    const int r16 = lane & 15, kq = lane >> 4;
    const size_t kb = (size_t)c * NTM * DIM;
    const int row0 = (w << 5) + (lane >> 2), row1 = row0 + 16;
    const int sc0 = ((lane & 3) ^ ((row0 >> 1) & 3)) << 3;
    const int sc1 = ((lane & 3) ^ ((row1 >> 1) & 3)) << 3;
    const unsigned short* gA0 = q2pb + (size_t)(m0 + row0) * DIM + sc0;
    const unsigned short* gA1 = q2pb + (size_t)(m0 + row1) * DIM + sc1;
    const unsigned short* gK0 = k2 + kb + (size_t)row0 * DIM + sc0;
    const unsigned short* gK1 = k2 + kb + (size_t)row1 * DIM + sc1;
    const bool kw = (w < 3);   // waves 0..2 stage the 96 K rows
    const int lw = w << 10;
    int offa[2], offk[6];
    #pragma unroll
    for (int i = 0; i < 2; i++) offa[i] = swz((mt0 + i) * 16 + r16, kq);
    #pragma unroll
    for (int j = 0; j < 6; j++) offk[j] = swz(j * 16 + r16, kq);
    f32x4 acc[2][6] = {};

    gload16(gA0, AsBuf[0] + lw);
    gload16(gA1, AsBuf[0] + lw + 512);
    if (kw) {
        gload16(gK0, KsBuf[0] + lw);
        gload16(gK1, KsBuf[0] + lw + 512);
    }
    __syncthreads();

    #pragma unroll
    for (int t = 0; t < 16; t++) {
        const int cur = t & 1, nxt = cur ^ 1;
        if (t < 15) {
            const int ko = (t + 1) << 5;
            gload16(gA0 + ko, AsBuf[nxt] + lw);
            gload16(gA1 + ko, AsBuf[nxt] + lw + 512);
            if (kw) {
                gload16(gK0 + ko, KsBuf[nxt] + lw);
                gload16(gK1 + ko, KsBuf[nxt] + lw + 512);
            }
        }
        bf16x8 af[2], bfr[6];
        #pragma unroll
        for (int i = 0; i < 2; i++)
            af[i] = *(const bf16x8*)(AsBuf[cur] + offa[i]);
        #pragma unroll
        for (int j = 0; j < 6; j++)
            bfr[j] = *(const bf16x8*)(KsBuf[cur] + offk[j]);
        __builtin_amdgcn_s_setprio(1);
        #pragma unroll
        for (int j = 0; j < 6; j++) {
            acc[0][j] = __builtin_amdgcn_mfma_f32_16x16x32_bf16(af[0], bfr[j], acc[0][j], 0, 0, 0);
            acc[1][j] = __builtin_amdgcn_mfma_f32_16x16x32_bf16(af[1], bfr[j], acc[1][j], 0, 0, 0);
        }
        __builtin_amdgcn_s_setprio(0);
        if (t < 15) __syncthreads();
    }

    // in-register softmax over m (12 values per (row,t), split across lane pair lane^8)
    #pragma unroll
    for (int i = 0; i < 2; i++) {
        #pragma unroll
        for (int rr = 0; rr < 4; rr++) {
            float v0 = acc[i][0][rr], v1 = acc[i][1][rr], v2 = acc[i][2][rr];
            float v3 = acc[i][3][rr], v4 = acc[i][4][rr], v5 = acc[i][5][rr];
            float mx = fmaxf(fmaxf(fmaxf(v0, v1), fmaxf(v2, v3)), fmaxf(v4, v5));
            mx = fmaxf(mx, __shfl_xor(mx, 8, 64));
            float e0 = __expf(v0 - mx), e1 = __expf(v1 - mx), e2 = __expf(v2 - mx);
            float e3 = __expf(v3 - mx), e4 = __expf(v4 - mx), e5 = __expf(v5 - mx);
            float s = e0 + e1 + e2 + e3 + e4 + e5;
            s += __shfl_xor(s, 8, 64);
            float inv = 1.f / (96.f * s);
            acc[i][0][rr] = e0 * inv; acc[i][1][rr] = e1 * inv; acc[i][2][rr] = e2 * inv;
            acc[i][3][rr] = e3 * inv; acc[i][4][rr] = e4 * inv; acc[i][5][rr] = e5 * inv;
        }
    }

    // sum over l: in-lane over 4 rows (groups 0..2 = l 0..11; group 3 = pad),
    // then across row-groups via shfl_xor(16/32).
    const bool contrib = (lane >> 4) < 3;
    #pragma unroll
    for (int i = 0; i < 2; i++) {
        float s6[6];
        #pragma unroll
        for (int j = 0; j < 6; j++) {
            float t = contrib ? (acc[i][j][0] + acc[i][j][1] + acc[i][j][2] + acc[i][j][3]) : 0.f;
            t += __shfl_xor(t, 16, 64);
            t += __shfl_xor(t, 32, 64);
            s6[j] = t;
        }
        if (lane < 16) {
            const int b = bg * 8 + mt0 + i;
            float* dst = wout + ((size_t)(b * NCLS + c)) * NTM;
            #pragma unroll
            for (int j = 0; j < 6; j++)
                dst[j * 16 + r16] = s6[j];
        }
    }
}

// ---------- txt[b,c,:] = sum_tm w[b,c,tm] * v2p[c,tm,:] + cob ; block=(c, 16 batches) ----------
__global__ __launch_bounds__(256)
void txt_kernel(const float* __restrict__ wbuf, const unsigned short* __restrict__ v2p,
                const float* __restrict__ cob, unsigned short* __restrict__ txt)
{
    __shared__ float ws[16 * NTM];
    const int c = blockIdx.x, bg = blockIdx.y, tid = threadIdx.x;
    for (int idx = tid; idx < 16 * NTM; idx += 256) {
        int bl = idx / NTM, tm = idx - bl * NTM;
        ws[idx] = wbuf[((size_t)((bg * 16 + bl) * NCLS + c)) * NTM + tm];
    }
    __syncthreads();
    float a0[16] = {}, a1[16] = {};
    const unsigned int* vrow = (const unsigned int*)(v2p + (size_t)c * NTM * DIM) + tid;
    for (int tm = 0; tm < NTM; tm++) {
        unsigned int u = vrow[tm * 256];
        float vx = __uint_as_float(u << 16);
        float vy = __uint_as_float(u & 0xFFFF0000u);
        #pragma unroll
        for (int bl = 0; bl < 16; bl++) {
            float wv = ws[bl * NTM + tm];
            a0[bl] += wv * vx; a1[bl] += wv * vy;
        }
    }
    int d0 = tid * 2;
    float c0 = cob[d0], c1 = cob[d0 + 1];
    #pragma unroll
    for (int bl = 0; bl < 16; bl++) {
        int b = bg * 16 + bl;
        unsigned int o = (unsigned int)f2bf(a0[bl] + c0) | ((unsigned int)f2bf(a1[bl] + c1) << 16);
        ((unsigned int*)txt)[(size_t)(b * NCLS + c) * 256 + tid] = o;
    }
}

// ---------- n2[b,d] = sum_c txt[b,c,d]^2 ----------
__global__ __launch_bounds__(256)
void n2_kernel(const unsigned short* __restrict__ txt, float* __restrict__ n2)
{
    const int b = blockIdx.x, cg = blockIdx.y, t = threadIdx.x;
    float a0 = 0.f, a1 = 0.f;
    const unsigned int* p = (const unsigned int*)txt + ((size_t)(b * NCLS + cg * 125)) * 256 + t;
    for (int c = 0; c < 125; c++) {
        unsigned int u = p[c * 256];
        float vx = __uint_as_float(u << 16);
        float vy = __uint_as_float(u & 0xFFFF0000u);
        a0 += vx * vx; a1 += vy * vy;
    }
    atomicAdd(&n2[b * DIM + t * 2], a0);
    atomicAdd(&n2[b * DIM + t * 2 + 1], a1);
}

// ---------- u[b,d] = exp(ls) * img_n[b,d] / sqrt(n2[b,d]) ----------
__global__ __launch_bounds__(256)
void u_kernel(const float* __restrict__ imgn, const float* __restrict__ n2,
              const float* __restrict__ logit_scale, float* __restrict__ u)
{
    int i = blockIdx.x * 256 + threadIdx.x;
    float els = expf(logit_scale[0]);
    u[i] = els * imgn[i] * rsqrtf(n2[i]);
}

// ---------- logits[b,c] = sum_d u[b,d] * txt[b,c,d] ----------
__global__ __launch_bounds__(256)
void logits_kernel(const unsigned short* __restrict__ txt, const float* __restrict__ u,
                   float* __restrict__ out)
{
    __shared__ float lu[DIM];
    const int b = blockIdx.y, cg = blockIdx.x, tid = threadIdx.x;
    lu[tid]       = u[b*DIM + tid];
    lu[tid + 256] = u[b*DIM + tid + 256];
    __syncthreads();
    int wave = tid >> 6, lane = tid & 63;
    int c = (cg << 2) + wave;
    const unsigned short* row = txt + (size_t)(b * NCLS + c) * DIM;
    ushort4 p0 = ((const ushort4*)row)[lane*2];
    ushort4 p1 = ((const ushort4*)row)[lane*2 + 1];
    int d0 = lane * 8;
    float s = bf2f(p0.x)*lu[d0]   + bf2f(p0.y)*lu[d0+1] + bf2f(p0.z)*lu[d0+2] + bf2f(p0.w)*lu[d0+3]
            + bf2f(p1.x)*lu[d0+4] + bf2f(p1.y)*lu[d0+5] + bf2f(p1.z)*lu[d0+6] + bf2f(p1.w)*lu[d0+7];
    #pragma unroll
    for (int off = 32; off > 0; off >>= 1) s += __shfl_down(s, off, 64);
    if (lane == 0) out[b*NCLS + c] = s;
}

extern "C" void kernel_launch(void* const* d_in, const int* in_sizes, int n_in,
                              void* d_out, int out_size, void* d_ws, size_t ws_size,
                              hipStream_t stream)
{
    const float* x   = (const float*)d_in[0];
    const float* tfe = (const float*)d_in[1];
    const float* siw = (const float*)d_in[2];
    const float* sib = (const float*)d_in[3];
    const float* sow = (const float*)d_in[4];
    const float* sob = (const float*)d_in[5];
    const float* ciw = (const float*)d_in[6];
    const float* cib = (const float*)d_in[7];
    const float* cow = (const float*)d_in[8];
    const float* cob = (const float*)d_in[9];
    const float* ls  = (const float*)d_in[10];
    float* out = (float*)d_out;

    char* p = (char*)d_ws;
    auto alloc = [&](size_t bytes) { char* r = p; p += (bytes + 255) & ~255ull; return r; };
    unsigned short* tfeb = (unsigned short*)alloc((size_t)49152000 * 2);   // 98.3 MB
    unsigned short* k2   = (unsigned short*)alloc((size_t)96000 * DIM * 2);
    unsigned short* v2p  = (unsigned short*)alloc((size_t)96000 * DIM * 2);
    float* wbuf          = (float*)alloc((size_t)BATCH * NCLS * NTM * 4);  // 24.6 MB
    float* qkv           = (float*)alloc((size_t)768 * 1536 * 4);
    float* ao            = (float*)alloc((size_t)768 * DIM * 4);
    float* xs            = (float*)alloc((size_t)768 * DIM * 4);
    float* q2s           = (float*)alloc((size_t)768 * DIM * 4);
    unsigned short* q2pb = (unsigned short*)alloc((size_t)1024 * DIM * 2);
    unsigned short* cWkb = (unsigned short*)alloc((size_t)DIM * DIM * 2);
    unsigned short* Wvob = (unsigned short*)alloc((size_t)DIM * DIM * 2);
    float* bvo           = (float*)alloc(DIM * 4);
    float* n2            = (float*)alloc(BATCH * DIM * 4);
    float* uu            = (float*)alloc(BATCH * DIM * 4);
    float* imgn          = (float*)alloc(BATCH * DIM * 4);
    unsigned short* txt  = tfeb;   // alias: tfeb dead after v2p GEMM, txt written after

    hipMemsetAsync(n2, 0, BATCH * DIM * 4, stream);

    // weight/text prep
    f2bf_kernel<<<48000, 256, 0, stream>>>(tfe, tfeb, 49152000);
    f2bf_kernel<<<256, 256, 0, stream>>>(ciw + 512*512, cWkb, 262144);
    fold_wvo<<<512, 256, 0, stream>>>(cow, ciw + 1024*512, cib + 1024, Wvob, bvo);

    // self-attn head (fp32, small)
    gemm_bt_f32<<<dim3(24, 12), 256, 0, stream>>>(x, siw, sib, qkv, 768, 1536, 512, 1.f);
    attn_kernel<<<64, 256, 0, stream>>>(qkv, ao);
    gemm_bt_f32<<<dim3(8, 12), 256, 0, stream>>>(ao, sow, sob, xs, 768, 512, 512, 1.f);
    img_kernel<<<64, 256, 0, stream>>>(xs, imgn);
    gemm_bt_f32<<<dim3(8, 12), 256, 0, stream>>>(xs, ciw, cib, q2s, 768, 512, 512, SCALEF);
    build_q2p<<<dim3(16, 64), 256, 0, stream>>>(q2s, q2pb);

    // k2 / v2' projections (MFMA, async global_load_lds staging, 2-D grid)
    gemm_mfma<unsigned short><<<dim3(4, 750), 256, 0, stream>>>(
        tfeb, cWkb, cib + 512, k2, 96000, 512, 1.f);
    gemm_mfma<unsigned short><<<dim3(4, 750), 256, 0, stream>>>(
        tfeb, Wvob, bvo, v2p, 96000, 512, 1.f);

    // fused scores+softmax -> w[b,c,96]  (XCD-grouped 1-D grid)
    fused_scores<<<8000, 256, 0, stream>>>(q2pb, k2, wbuf);

    // txt = w @ v2' + cob  (bf16), then norms and logits
    txt_kernel<<<dim3(1000, 4), 256, 0, stream>>>(wbuf, v2p, cob, txt);
    n2_kernel<<<dim3(64, 8), 256, 0, stream>>>(txt, n2);
    u_kernel<<<128, 256, 0, stream>>>(imgn, n2, ls, uu);
    logits_kernel<<<dim3(250, 64), 256, 0, stream>>>(txt, uu, out);
}

// Round 6
// 816.565 us; speedup vs baseline: 1.4183x; 1.0984x over previous
//
#include <hip/hip_runtime.h>

#define L_IMG 12
#define BATCH 64
#define NCLS  1000
#define DIM   512
#define NTM   96
#define SCALEF 0.044194173824159216f   // 1/sqrt(512)

typedef __attribute__((ext_vector_type(8))) short bf16x8;
typedef __attribute__((ext_vector_type(4))) float f32x4;

// ---------- bf16 helpers ----------
__device__ __forceinline__ float bf2f(unsigned short u) {
    return __uint_as_float(((unsigned int)u) << 16);
}
__device__ __forceinline__ unsigned short f2bf(float f) {
    unsigned int u = __float_as_uint(f);
    u += 0x7FFFu + ((u >> 16) & 1u);
    return (unsigned short)(u >> 16);
}
__device__ __forceinline__ void storeo(float* p, float v) { *p = v; }
__device__ __forceinline__ void storeo(unsigned short* p, float v) { *p = f2bf(v); }

// XOR-swizzled LDS offset (shorts) for [row][32-short] tiles: 16B unit u ^= (row>>1)&3.
// ds_read frags (16-lane phase, fixed kq) are uniform 2-way (free).
__device__ __forceinline__ int swz(int row, int u) {
    return (row << 5) + ((u ^ ((row >> 1) & 3)) << 3);
}

// async global->LDS, 16 B per lane; LDS dest = wave-uniform base + lane*16 (linear).
// Swizzle achieved by inverse-permuting the per-lane GLOBAL source (rule #21).
__device__ __forceinline__ void gload16(const unsigned short* g, unsigned short* l) {
    __builtin_amdgcn_global_load_lds(
        (const __attribute__((address_space(1))) void*)g,
        (__attribute__((address_space(3))) void*)l, 16, 0, 0);
}

// ---------- fp32 -> bf16 convert (n multiple of 4) ----------
__global__ __launch_bounds__(256)
void f2bf_kernel(const float* __restrict__ in, unsigned short* __restrict__ out, int n)
{
    int i = (blockIdx.x * 256 + threadIdx.x) * 4;
    if (i < n) {
        float4 v = *(const float4*)(in + i);
        ushort4 o;
        o.x = f2bf(v.x); o.y = f2bf(v.y); o.z = f2bf(v.z); o.w = f2bf(v.w);
        *(ushort4*)(out + i) = o;
    }
}

// ---------- Wvo[d,k] = sum_e cow[d,e]*cWv[e,k] (bf16 out), bvo[d] = sum_e cow[d,e]*cbv[e] ----------
__global__ __launch_bounds__(256)
void fold_wvo(const float* __restrict__ cow, const float* __restrict__ cWv,
              const float* __restrict__ cbv, unsigned short* __restrict__ Wvob,
              float* __restrict__ bvo)
{
    __shared__ float crow[DIM];
    __shared__ float red[256];
    const int d = blockIdx.x, t = threadIdx.x;
    float c0 = cow[d * DIM + t], c1 = cow[d * DIM + t + 256];
    crow[t] = c0; crow[t + 256] = c1;
    red[t] = c0 * cbv[t] + c1 * cbv[t + 256];
    __syncthreads();
    for (int s = 128; s > 0; s >>= 1) {
        if (t < s) red[t] += red[t + s];
        __syncthreads();
    }
    if (t == 0) bvo[d] = red[0];
    float a0 = 0.f, a1 = 0.f;
    for (int e = 0; e < DIM; e++) {
        float ce = crow[e];
        a0 += ce * cWv[e * DIM + t];
        a1 += ce * cWv[e * DIM + t + 256];
    }
    Wvob[d * DIM + t]       = f2bf(a0);
    Wvob[d * DIM + t + 256] = f2bf(a1);
}

// ---------- small fp32 tiled GEMM: C[M,N] = (A[M,K] @ W[N,K]^T + bias) * scale ----------
#define BKT 32
#define LDT 68
__global__ __launch_bounds__(256)
void gemm_bt_f32(const float* __restrict__ A, const float* __restrict__ W,
                 const float* __restrict__ bias, float* __restrict__ Co,
                 int M, int N, int K, float out_scale)
{
    __shared__ float As[BKT * LDT];
    __shared__ float Ws[BKT * LDT];
    const int tid = threadIdx.x;
    const int m0 = blockIdx.y << 6, n0 = blockIdx.x << 6;
    const int tx = tid & 15, ty = tid >> 4;
    float acc[4][4] = {};
    for (int k0 = 0; k0 < K; k0 += BKT) {
        #pragma unroll
        for (int i = 0; i < 2; i++) {
            int slot = tid + (i << 8);
            int r = slot >> 3, kq = slot & 7;
            float4 v = *(const float4*)(A + (size_t)(m0 + r) * K + k0 + (kq << 2));
            As[(kq*4+0)*LDT + r] = v.x; As[(kq*4+1)*LDT + r] = v.y;
            As[(kq*4+2)*LDT + r] = v.z; As[(kq*4+3)*LDT + r] = v.w;
            float4 w = *(const float4*)(W + (size_t)(n0 + r) * K + k0 + (kq << 2));
            Ws[(kq*4+0)*LDT + r] = w.x; Ws[(kq*4+1)*LDT + r] = w.y;
            Ws[(kq*4+2)*LDT + r] = w.z; Ws[(kq*4+3)*LDT + r] = w.w;
        }
        __syncthreads();
        #pragma unroll
        for (int kk = 0; kk < BKT; kk++) {
            float4 a = *(const float4*)(As + kk*LDT + ty*4);
            float4 w = *(const float4*)(Ws + kk*LDT + tx*4);
            acc[0][0] += a.x*w.x; acc[0][1] += a.x*w.y; acc[0][2] += a.x*w.z; acc[0][3] += a.x*w.w;
            acc[1][0] += a.y*w.x; acc[1][1] += a.y*w.y; acc[1][2] += a.y*w.z; acc[1][3] += a.y*w.w;
            acc[2][0] += a.z*w.x; acc[2][1] += a.z*w.y; acc[2][2] += a.z*w.z; acc[2][3] += a.z*w.w;
            acc[3][0] += a.w*w.x; acc[3][1] += a.w*w.y; acc[3][2] += a.w*w.z; acc[3][3] += a.w*w.w;
        }
        __syncthreads();
    }
    #pragma unroll
    for (int i = 0; i < 4; i++) {
        int mr = m0 + ty*4 + i;
        #pragma unroll
        for (int j = 0; j < 4; j++) {
            int n = n0 + tx*4 + j;
            float v = acc[i][j];
            if (bias) v += bias[n];
            Co[(size_t)mr * N + n] = v * out_scale;
        }
    }
}

// ---------- small fp32 GEMM, B NOT transposed: C[M,N] = A[M,K] @ W[K,N] ----------
// Used to fold cWk into the query side: q2k = q2s @ cWk (k-bias cancels in softmax).
__global__ __launch_bounds__(256)
void gemm_nt_f32(const float* __restrict__ A, const float* __restrict__ W,
                 float* __restrict__ Co, int M, int N, int K)
{
    __shared__ float As[BKT * LDT];
    __shared__ float Ws[BKT * LDT];
    const int tid = threadIdx.x;
    const int m0 = blockIdx.y << 6, n0 = blockIdx.x << 6;
    const int tx = tid & 15, ty = tid >> 4;
    float acc[4][4] = {};
    for (int k0 = 0; k0 < K; k0 += BKT) {
        #pragma unroll
        for (int i = 0; i < 2; i++) {
            int slot = tid + (i << 8);
            int r = slot >> 3, kq = slot & 7;
            float4 v = *(const float4*)(A + (size_t)(m0 + r) * K + k0 + (kq << 2));
            As[(kq*4+0)*LDT + r] = v.x; As[(kq*4+1)*LDT + r] = v.y;
            As[(kq*4+2)*LDT + r] = v.z; As[(kq*4+3)*LDT + r] = v.w;
            int kr = slot >> 4, c4 = slot & 15;   // 32 k-rows x 16 float4 over n
            *(float4*)(Ws + kr*LDT + c4*4) =
                *(const float4*)(W + (size_t)(k0 + kr) * N + n0 + (c4 << 2));
        }
        __syncthreads();
        #pragma unroll
        for (int kk = 0; kk < BKT; kk++) {
            float4 a = *(const float4*)(As + kk*LDT + ty*4);
            float4 w = *(const float4*)(Ws + kk*LDT + tx*4);
            acc[0][0] += a.x*w.x; acc[0][1] += a.x*w.y; acc[0][2] += a.x*w.z; acc[0][3] += a.x*w.w;
            acc[1][0] += a.y*w.x; acc[1][1] += a.y*w.y; acc[1][2] += a.y*w.z; acc[1][3] += a.y*w.w;
            acc[2][0] += a.z*w.x; acc[2][1] += a.z*w.y; acc[2][2] += a.z*w.z; acc[2][3] += a.z*w.w;
            acc[3][0] += a.w*w.x; acc[3][1] += a.w*w.y; acc[3][2] += a.w*w.z; acc[3][3] += a.w*w.w;
        }
        __syncthreads();
    }
    #pragma unroll
    for (int i = 0; i < 4; i++) {
        int mr = m0 + ty*4 + i;
        #pragma unroll
        for (int j = 0; j < 4; j++)
            Co[(size_t)mr * N + n0 + tx*4 + j] = acc[i][j];
    }
}

// ---------- self-attention over the 12-layer axis, one block per batch ----------
__global__ __launch_bounds__(256)
void attn_kernel(const float* __restrict__ qkv, float* __restrict__ ao)
{
    __shared__ float lq[L_IMG * DIM];
    __shared__ float lk[L_IMG * DIM];
    __shared__ float sc[L_IMG * L_IMG];
    __shared__ float sa[L_IMG * L_IMG];
    const int b = blockIdx.x, tid = threadIdx.x;
    for (int i = 0; i < 6; i++) {
        int slot = tid + (i << 8);
        int l = slot >> 7, e4 = slot & 127;
        const float* row = qkv + (size_t)(l * BATCH + b) * 1536;
        *(float4*)(lq + l*DIM + e4*4) = *(const float4*)(row + e4*4);
        *(float4*)(lk + l*DIM + e4*4) = *(const float4*)(row + DIM + e4*4);
    }
    __syncthreads();
    if (tid < 144) {
        int l = tid / 12, m = tid % 12;
        float a = 0.f;
        for (int d4 = 0; d4 < 128; d4++) {
            float4 q = *(const float4*)(lq + l*DIM + d4*4);
            float4 k = *(const float4*)(lk + m*DIM + d4*4);
            a += q.x*k.x + q.y*k.y + q.z*k.z + q.w*k.w;
        }
        sc[tid] = a * SCALEF;
    }
    __syncthreads();
    if (tid < 12) {
        float mx = -1e30f;
        for (int m = 0; m < 12; m++) mx = fmaxf(mx, sc[tid*12 + m]);
        float e[12], s = 0.f;
        for (int m = 0; m < 12; m++) { e[m] = __expf(sc[tid*12 + m] - mx); s += e[m]; }
        float inv = 1.f / s;
        for (int m = 0; m < 12; m++) sa[tid*12 + m] = e[m] * inv;
    }
    __syncthreads();
    for (int i = 0; i < 2; i++) {
        int e = tid + (i << 8);
        float vv[12];
        #pragma unroll
        for (int m = 0; m < 12; m++)
            vv[m] = qkv[(size_t)(m * BATCH + b) * 1536 + 1024 + e];
        #pragma unroll
        for (int l = 0; l < 12; l++) {
            float a = 0.f;
            #pragma unroll
            for (int m = 0; m < 12; m++) a += sa[l*12 + m] * vv[m];
            ao[(size_t)(l * BATCH + b) * DIM + e] = a;
        }
    }
}

// ---------- normalize image features (xs layer 11) ----------
__global__ __launch_bounds__(256)
void img_kernel(const float* __restrict__ xs, float* __restrict__ imgn)
{
    __shared__ float red[256];
    const int b = blockIdx.x, tid = threadIdx.x;
    const float* row = xs + (size_t)(11 * BATCH + b) * DIM;
    float v0 = row[tid], v1 = row[tid + 256];
    red[tid] = v0*v0 + v1*v1;
    __syncthreads();
    for (int s = 128; s > 0; s >>= 1) {
        if (tid < s) red[tid] += red[tid + s];
        __syncthreads();
    }
    float inv = rsqrtf(red[0]);
    imgn[b*DIM + tid]       = v0 * inv;
    imgn[b*DIM + tid + 256] = v1 * inv;
}

// ---------- q2k fp32 [12,64,512] -> q2pb bf16 [64*16, 512], l>=12 zero ----------
__global__ __launch_bounds__(256)
void build_q2p(const float* __restrict__ q2s, unsigned short* __restrict__ q2pb)
{
    const int l = blockIdx.x, b = blockIdx.y, t = threadIdx.x;
    int d0 = t * 2;
    unsigned int o = 0;
    if (l < 12) {
        float2 v = *(const float2*)(q2s + (size_t)(l * BATCH + b) * DIM + d0);
        o = (unsigned int)f2bf(v.x) | ((unsigned int)f2bf(v.y) << 16);
    }
    ((unsigned int*)q2pb)[(size_t)(b * 16 + l) * 256 + t] = o;
}

// ---------- MFMA GEMM: C[M,N] = A[M,K]@W[N,K]^T + bias ; 128x128 tile, BK=32 ----------
// Staging via async global_load_lds width=16: linear LDS dest, inverse-swizzled
// per-lane global source, swizzled ds_read. Double-buffered, one barrier/iter.
template<typename OutT>
__global__ __launch_bounds__(256, 4)
void gemm_mfma(const unsigned short* __restrict__ A, const unsigned short* __restrict__ W,
               const float* __restrict__ bias, OutT* __restrict__ Co,
               int M, int N, float scale)
{
    const int K = DIM;
    __shared__ __align__(16) unsigned short AsBuf[2][128 * 32];
    __shared__ __align__(16) unsigned short WsBuf[2][128 * 32];
    const int m0 = blockIdx.y << 7, n0 = blockIdx.x << 7;
    const int tid = threadIdx.x;
    const int w = tid >> 6, lane = tid & 63;
    const int mt0 = (w & 1) * 4, nt0 = (w >> 1) * 4;
    const int r16 = lane & 15, kq = lane >> 4;
    const int row0 = (w << 5) + (lane >> 2), row1 = row0 + 16;
    const int sc0 = ((lane & 3) ^ ((row0 >> 1) & 3)) << 3;
    const int sc1 = ((lane & 3) ^ ((row1 >> 1) & 3)) << 3;
    const unsigned short* gA0 = A + (size_t)(m0 + row0) * K + sc0;
    const unsigned short* gA1 = A + (size_t)(m0 + row1) * K + sc1;
    const unsigned short* gW0 = W + (size_t)(n0 + row0) * K + sc0;
    const unsigned short* gW1 = W + (size_t)(n0 + row1) * K + sc1;
    const int lw = w << 10;
    int offa[4], offb[4];
    #pragma unroll
    for (int i = 0; i < 4; i++) {
        offa[i] = swz((mt0 + i) * 16 + r16, kq);
        offb[i] = swz((nt0 + i) * 16 + r16, kq);
    }
    f32x4 acc[4][4] = {};

    gload16(gA0, AsBuf[0] + lw);
    gload16(gA1, AsBuf[0] + lw + 512);
    gload16(gW0, WsBuf[0] + lw);
    gload16(gW1, WsBuf[0] + lw + 512);
    __syncthreads();

    #pragma unroll
    for (int t = 0; t < 16; t++) {
        const int cur = t & 1, nxt = cur ^ 1;
        if (t < 15) {
            const int ko = (t + 1) << 5;
            gload16(gA0 + ko, AsBuf[nxt] + lw);
            gload16(gA1 + ko, AsBuf[nxt] + lw + 512);
            gload16(gW0 + ko, WsBuf[nxt] + lw);
            gload16(gW1 + ko, WsBuf[nxt] + lw + 512);
        }
        bf16x8 af[4], bfr[4];
        #pragma unroll
        for (int i = 0; i < 4; i++) {
            af[i]  = *(const bf16x8*)(AsBuf[cur] + offa[i]);
            bfr[i] = *(const bf16x8*)(WsBuf[cur] + offb[i]);
        }
        #pragma unroll
        for (int i = 0; i < 4; i++)
            #pragma unroll
            for (int j = 0; j < 4; j++)
                acc[i][j] = __builtin_amdgcn_mfma_f32_16x16x32_bf16(af[i], bfr[j], acc[i][j], 0, 0, 0);
        if (t < 15) __syncthreads();
    }
    const int rbase = (lane >> 4) * 4;
    #pragma unroll
    for (int i = 0; i < 4; i++)
        #pragma unroll
        for (int j = 0; j < 4; j++) {
            int gcol = n0 + (nt0 + j) * 16 + r16;
            float bv = bias ? bias[gcol] : 0.f;
            #pragma unroll
            for (int r = 0; r < 4; r++) {
                int grow = m0 + (mt0 + i) * 16 + rbase + r;
                storeo(Co + (size_t)grow * N + gcol, acc[i][j][r] * scale + bv);
            }
        }
}

// ---------- fused scores + softmax(m) + sum_l: one block = (class c, 8 batches) ----------
// K-source is tfeb DIRECTLY (cWk folded into the query side; k-bias cancels in softmax).
// Async global_load_lds staging; XCD-grouped 1-D grid (8 bg-blocks of a class share an XCD).
// Softmax over m fully in registers; sum_l via shfl_xor(16/32), pad row-group masked.
__global__ __launch_bounds__(256, 5)
void fused_scores(const unsigned short* __restrict__ q2pb, const unsigned short* __restrict__ k2,
                  float* __restrict__ wout)
{
    __shared__ __align__(16) unsigned short AsBuf[2][128 * 32];  // 2 x 8192 B
    __shared__ __align__(16) unsigned short KsBuf[2][96 * 32];   // 2 x 6144 B
    const int bid = blockIdx.x;
    const int g = bid >> 6, r = bid & 63;
    const int c = g * 8 + (r & 7), bg = r >> 3;
    const int tid = threadIdx.x;
    const int m0 = bg << 7;
    const int w = tid >> 6, lane = tid & 63;
    const int mt0 = w * 2;
    const int r16 = lane & 15, kq = lane >> 4;
    const size_t kb = (size_t)c * NTM * DIM;
    const int row0 = (w << 5) + (lane >> 2), row1 = row0 + 16;
    const int sc0 = ((lane & 3) ^ ((row0 >> 1) & 3)) << 3;
    const int sc1 = ((lane & 3) ^ ((row1 >> 1) & 3)) << 3;
    const unsigned short* gA0 = q2pb + (size_t)(m0 + row0) * DIM + sc0;
    const unsigned short* gA1 = q2pb + (size_t)(m0 + row1) * DIM + sc1;
    const unsigned short* gK0 = k2 + kb + (size_t)row0 * DIM + sc0;
    const unsigned short* gK1 = k2 + kb + (size_t)row1 * DIM + sc1;
    const bool kw = (w < 3);   // waves 0..2 stage the 96 K rows
    const int lw = w << 10;
    int offa[2], offk[6];
    #pragma unroll
    for (int i = 0; i < 2; i++) offa[i] = swz((mt0 + i) * 16 + r16, kq);
    #pragma unroll
    for (int j = 0; j < 6; j++) offk[j] = swz(j * 16 + r16, kq);
    f32x4 acc[2][6] = {};

    gload16(gA0, AsBuf[0] + lw);
    gload16(gA1, AsBuf[0] + lw + 512);
    if (kw) {
        gload16(gK0, KsBuf[0] + lw);
        gload16(gK1, KsBuf[0] + lw + 512);
    }
    __syncthreads();

    #pragma unroll
    for (int t = 0; t < 16; t++) {
        const int cur = t & 1, nxt = cur ^ 1;
        if (t < 15) {
            const int ko = (t + 1) << 5;
            gload16(gA0 + ko, AsBuf[nxt] + lw);
            gload16(gA1 + ko, AsBuf[nxt] + lw + 512);
            if (kw) {
                gload16(gK0 + ko, KsBuf[nxt] + lw);
                gload16(gK1 + ko, KsBuf[nxt] + lw + 512);
            }
        }
        bf16x8 af[2], bfr[6];
        #pragma unroll
        for (int i = 0; i < 2; i++)
            af[i] = *(const bf16x8*)(AsBuf[cur] + offa[i]);
        #pragma unroll
        for (int j = 0; j < 6; j++)
            bfr[j] = *(const bf16x8*)(KsBuf[cur] + offk[j]);
        __builtin_amdgcn_s_setprio(1);
        #pragma unroll
        for (int j = 0; j < 6; j++) {
            acc[0][j] = __builtin_amdgcn_mfma_f32_16x16x32_bf16(af[0], bfr[j], acc[0][j], 0, 0, 0);
            acc[1][j] = __builtin_amdgcn_mfma_f32_16x16x32_bf16(af[1], bfr[j], acc[1][j], 0, 0, 0);
        }
        __builtin_amdgcn_s_setprio(0);
        if (t < 15) __syncthreads();
    }

    // in-register softmax over m (12 values per (row,t), split across lane pair lane^8)
    #pragma unroll
    for (int i = 0; i < 2; i++) {
        #pragma unroll
        for (int rr = 0; rr < 4; rr++) {
            float v0 = acc[i][0][rr], v1 = acc[i][1][rr], v2 = acc[i][2][rr];
            float v3 = acc[i][3][rr], v4 = acc[i][4][rr], v5 = acc[i][5][rr];
            float mx = fmaxf(fmaxf(fmaxf(v0, v1), fmaxf(v2, v3)), fmaxf(v4, v5));
            mx = fmaxf(mx, __shfl_xor(mx, 8, 64));
            float e0 = __expf(v0 - mx), e1 = __expf(v1 - mx), e2 = __expf(v2 - mx);
            float e3 = __expf(v3 - mx), e4 = __expf(v4 - mx), e5 = __expf(v5 - mx);
            float s = e0 + e1 + e2 + e3 + e4 + e5;
            s += __shfl_xor(s, 8, 64);
            float inv = 1.f / (96.f * s);
            acc[i][0][rr] = e0 * inv; acc[i][1][rr] = e1 * inv; acc[i][2][rr] = e2 * inv;
            acc[i][3][rr] = e3 * inv; acc[i][4][rr] = e4 * inv; acc[i][5][rr] = e5 * inv;
        }
    }

    // sum over l: in-lane over 4 rows (groups 0..2 = l 0..11; group 3 = pad),
    // then across row-groups via shfl_xor(16/32).
    const bool contrib = (lane >> 4) < 3;
    #pragma unroll
    for (int i = 0; i < 2; i++) {
        float s6[6];
        #pragma unroll
        for (int j = 0; j < 6; j++) {
            float t = contrib ? (acc[i][j][0] + acc[i][j][1] + acc[i][j][2] + acc[i][j][3]) : 0.f;
            t += __shfl_xor(t, 16, 64);
            t += __shfl_xor(t, 32, 64);
            s6[j] = t;
        }
        if (lane < 16) {
            const int b = bg * 8 + mt0 + i;
            float* dst = wout + ((size_t)(b * NCLS + c)) * NTM;
            #pragma unroll
            for (int j = 0; j < 6; j++)
                dst[j * 16 + r16] = s6[j];
        }
    }
}

// ---------- txt[b,c,:] = sum_tm w[b,c,tm] * v2p[c,tm,:] + cob ; block=(c, 16 batches) ----------
__global__ __launch_bounds__(256)
void txt_kernel(const float* __restrict__ wbuf, const unsigned short* __restrict__ v2p,
                const float* __restrict__ cob, unsigned short* __restrict__ txt)
{
    __shared__ float ws[16 * NTM];
    const int c = blockIdx.x, bg = blockIdx.y, tid = threadIdx.x;
    for (int idx = tid; idx < 16 * NTM; idx += 256) {
        int bl = idx / NTM, tm = idx - bl * NTM;
        ws[idx] = wbuf[((size_t)((bg * 16 + bl) * NCLS + c)) * NTM + tm];
    }
    __syncthreads();
    float a0[16] = {}, a1[16] = {};
    const unsigned int* vrow = (const unsigned int*)(v2p + (size_t)c * NTM * DIM) + tid;
    for (int tm = 0; tm < NTM; tm++) {
        unsigned int u = vrow[tm * 256];
        float vx = __uint_as_float(u << 16);
        float vy = __uint_as_float(u & 0xFFFF0000u);
        #pragma unroll
        for (int bl = 0; bl < 16; bl++) {
            float wv = ws[bl * NTM + tm];
            a0[bl] += wv * vx; a1[bl] += wv * vy;
        }
    }
    int d0 = tid * 2;
    float c0 = cob[d0], c1 = cob[d0 + 1];
    #pragma unroll
    for (int bl = 0; bl < 16; bl++) {
        int b = bg * 16 + bl;
        unsigned int o = (unsigned int)f2bf(a0[bl] + c0) | ((unsigned int)f2bf(a1[bl] + c1) << 16);
        ((unsigned int*)txt)[(size_t)(b * NCLS + c) * 256 + tid] = o;
    }
}

// ---------- n2[b,d] = sum_c txt[b,c,d]^2 ----------
__global__ __launch_bounds__(256)
void n2_kernel(const unsigned short* __restrict__ txt, float* __restrict__ n2)
{
    const int b = blockIdx.x, cg = blockIdx.y, t = threadIdx.x;
    float a0 = 0.f, a1 = 0.f;
    const unsigned int* p = (const unsigned int*)txt + ((size_t)(b * NCLS + cg * 125)) * 256 + t;
    for (int c = 0; c < 125; c++) {
        unsigned int u = p[c * 256];
        float vx = __uint_as_float(u << 16);
        float vy = __uint_as_float(u & 0xFFFF0000u);
        a0 += vx * vx; a1 += vy * vy;
    }
    atomicAdd(&n2[b * DIM + t * 2], a0);
    atomicAdd(&n2[b * DIM + t * 2 + 1], a1);
}

// ---------- u[b,d] = exp(ls) * img_n[b,d] / sqrt(n2[b,d]) ----------
__global__ __launch_bounds__(256)
void u_kernel(const float* __restrict__ imgn, const float* __restrict__ n2,
              const float* __restrict__ logit_scale, float* __restrict__ u)
{
    int i = blockIdx.x * 256 + threadIdx.x;
    float els = expf(logit_scale[0]);
    u[i] = els * imgn[i] * rsqrtf(n2[i]);
}

// ---------- logits[b,c] = sum_d u[b,d] * txt[b,c,d] ----------
__global__ __launch_bounds__(256)
void logits_kernel(const unsigned short* __restrict__ txt, const float* __restrict__ u,
                   float* __restrict__ out)
{
    __shared__ float lu[DIM];
    const int b = blockIdx.y, cg = blockIdx.x, tid = threadIdx.x;
    lu[tid]       = u[b*DIM + tid];
    lu[tid + 256] = u[b*DIM + tid + 256];
    __syncthreads();
    int wave = tid >> 6, lane = tid & 63;
    int c = (cg << 2) + wave;
    const unsigned short* row = txt + (size_t)(b * NCLS + c) * DIM;
    ushort4 p0 = ((const ushort4*)row)[lane*2];
    ushort4 p1 = ((const ushort4*)row)[lane*2 + 1];
    int d0 = lane * 8;
    float s = bf2f(p0.x)*lu[d0]   + bf2f(p0.y)*lu[d0+1] + bf2f(p0.z)*lu[d0+2] + bf2f(p0.w)*lu[d0+3]
            + bf2f(p1.x)*lu[d0+4] + bf2f(p1.y)*lu[d0+5] + bf2f(p1.z)*lu[d0+6] + bf2f(p1.w)*lu[d0+7];
    #pragma unroll
    for (int off = 32; off > 0; off >>= 1) s += __shfl_down(s, off, 64);
    if (lane == 0) out[b*NCLS + c] = s;
}

extern "C" void kernel_launch(void* const* d_in, const int* in_sizes, int n_in,
                              void* d_out, int out_size, void* d_ws, size_t ws_size,
                              hipStream_t stream)
{
    const float* x   = (const float*)d_in[0];
    const float* tfe = (const float*)d_in[1];
    const float* siw = (const float*)d_in[2];
    const float* sib = (const float*)d_in[3];
    const float* sow = (const float*)d_in[4];
    const float* sob = (const float*)d_in[5];
    const float* ciw = (const float*)d_in[6];
    const float* cib = (const float*)d_in[7];
    const float* cow = (const float*)d_in[8];
    const float* cob = (const float*)d_in[9];
    const float* ls  = (const float*)d_in[10];
    float* out = (float*)d_out;

    char* p = (char*)d_ws;
    auto alloc = [&](size_t bytes) { char* r = p; p += (bytes + 255) & ~255ull; return r; };
    unsigned short* tfeb = (unsigned short*)alloc((size_t)49152000 * 2);   // 98.3 MB
    unsigned short* v2p  = (unsigned short*)alloc((size_t)96000 * DIM * 2);
    float* wbuf          = (float*)alloc((size_t)BATCH * NCLS * NTM * 4);  // 24.6 MB
    float* qkv           = (float*)alloc((size_t)768 * 1536 * 4);
    float* ao            = (float*)alloc((size_t)768 * DIM * 4);
    float* xs            = (float*)alloc((size_t)768 * DIM * 4);
    float* q2s           = (float*)alloc((size_t)768 * DIM * 4);
    float* q2k           = (float*)alloc((size_t)768 * DIM * 4);
    unsigned short* q2pb = (unsigned short*)alloc((size_t)1024 * DIM * 2);
    unsigned short* Wvob = (unsigned short*)alloc((size_t)DIM * DIM * 2);
    float* bvo           = (float*)alloc(DIM * 4);
    float* n2            = (float*)alloc(BATCH * DIM * 4);
    float* uu            = (float*)alloc(BATCH * DIM * 4);
    float* imgn          = (float*)alloc(BATCH * DIM * 4);
    unsigned short* txt  = tfeb;   // alias: tfeb last read by fused_scores, txt written after

    hipMemsetAsync(n2, 0, BATCH * DIM * 4, stream);

    // weight/text prep
    f2bf_kernel<<<48000, 256, 0, stream>>>(tfe, tfeb, 49152000);
    fold_wvo<<<512, 256, 0, stream>>>(cow, ciw + 1024*512, cib + 1024, Wvob, bvo);

    // self-attn head (fp32, small)
    gemm_bt_f32<<<dim3(24, 12), 256, 0, stream>>>(x, siw, sib, qkv, 768, 1536, 512, 1.f);
    attn_kernel<<<64, 256, 0, stream>>>(qkv, ao);
    gemm_bt_f32<<<dim3(8, 12), 256, 0, stream>>>(ao, sow, sob, xs, 768, 512, 512, 1.f);
    img_kernel<<<64, 256, 0, stream>>>(xs, imgn);
    gemm_bt_f32<<<dim3(8, 12), 256, 0, stream>>>(xs, ciw, cib, q2s, 768, 512, 512, SCALEF);
    // fold cWk into query: q2k = q2s @ cWk   (k-bias cancels in softmax over m)
    gemm_nt_f32<<<dim3(8, 12), 256, 0, stream>>>(q2s, ciw + 512*512, q2k, 768, 512, 512);
    build_q2p<<<dim3(16, 64), 256, 0, stream>>>(q2k, q2pb);

    // v2' projection (MFMA, async global_load_lds staging)
    gemm_mfma<unsigned short><<<dim3(4, 750), 256, 0, stream>>>(
        tfeb, Wvob, bvo, v2p, 96000, 512, 1.f);

    // fused scores+softmax -> w[b,c,96]  (K = raw text features; XCD-grouped 1-D grid)
    fused_scores<<<8000, 256, 0, stream>>>(q2pb, tfeb, wbuf);

    // txt = w @ v2' + cob  (bf16), then norms and logits
    txt_kernel<<<dim3(1000, 4), 256, 0, stream>>>(wbuf, v2p, cob, txt);
    n2_kernel<<<dim3(64, 8), 256, 0, stream>>>(txt, n2);
    u_kernel<<<128, 256, 0, stream>>>(imgn, n2, ls, uu);
    logits_kernel<<<dim3(250, 64), 256, 0, stream>>>(txt, uu, out);
}

// Round 7
// 793.107 us; speedup vs baseline: 1.4602x; 1.0296x over previous
//
#include <hip/hip_runtime.h>

#define L_IMG 12
#define BATCH 64
#define NCLS  1000
#define DIM   512
#define NTM   96
#define SCALEF 0.044194173824159216f   // 1/sqrt(512)

typedef __attribute__((ext_vector_type(8))) short bf16x8;
typedef __attribute__((ext_vector_type(4))) float f32x4;

// ---------- bf16 helpers ----------
__device__ __forceinline__ float bf2f(unsigned short u) {
    return __uint_as_float(((unsigned int)u) << 16);
}
__device__ __forceinline__ unsigned short f2bf(float f) {
    unsigned int u = __float_as_uint(f);
    u += 0x7FFFu + ((u >> 16) & 1u);
    return (unsigned short)(u >> 16);
}
__device__ __forceinline__ void storeo(float* p, float v) { *p = v; }
__device__ __forceinline__ void storeo(unsigned short* p, float v) { *p = f2bf(v); }

// XOR-swizzled LDS offset (shorts) for [row][32-short] tiles: 16B unit u ^= (row>>1)&3.
__device__ __forceinline__ int swz(int row, int u) {
    return (row << 5) + ((u ^ ((row >> 1) & 3)) << 3);
}

// async global->LDS, 16 B per lane; LDS dest = wave-uniform base + lane*16 (linear).
// Swizzle achieved by inverse-permuting the per-lane GLOBAL source (rule #21).
__device__ __forceinline__ void gload16(const unsigned short* g, unsigned short* l) {
    __builtin_amdgcn_global_load_lds(
        (const __attribute__((address_space(1))) void*)g,
        (__attribute__((address_space(3))) void*)l, 16, 0, 0);
}

// ---------- fp32 -> bf16 convert (n multiple of 4) ----------
__global__ __launch_bounds__(256)
void f2bf_kernel(const float* __restrict__ in, unsigned short* __restrict__ out, int n)
{
    int i = (blockIdx.x * 256 + threadIdx.x) * 4;
    if (i < n) {
        float4 v = *(const float4*)(in + i);
        ushort4 o;
        o.x = f2bf(v.x); o.y = f2bf(v.y); o.z = f2bf(v.z); o.w = f2bf(v.w);
        *(ushort4*)(out + i) = o;
    }
}

// ---------- Wvo[d,k] = sum_e cow[d,e]*cWv[e,k] (bf16), bvo[d] = cow[d,:].cbv + cob[d] ----------
__global__ __launch_bounds__(256)
void fold_wvo(const float* __restrict__ cow, const float* __restrict__ cWv,
              const float* __restrict__ cbv, const float* __restrict__ cob,
              unsigned short* __restrict__ Wvob, float* __restrict__ bvo)
{
    __shared__ float crow[DIM];
    __shared__ float red[256];
    const int d = blockIdx.x, t = threadIdx.x;
    float c0 = cow[d * DIM + t], c1 = cow[d * DIM + t + 256];
    crow[t] = c0; crow[t + 256] = c1;
    red[t] = c0 * cbv[t] + c1 * cbv[t + 256];
    __syncthreads();
    for (int s = 128; s > 0; s >>= 1) {
        if (t < s) red[t] += red[t + s];
        __syncthreads();
    }
    if (t == 0) bvo[d] = red[0] + cob[d];
    float a0 = 0.f, a1 = 0.f;
    for (int e = 0; e < DIM; e++) {
        float ce = crow[e];
        a0 += ce * cWv[e * DIM + t];
        a1 += ce * cWv[e * DIM + t + 256];
    }
    Wvob[d * DIM + t]       = f2bf(a0);
    Wvob[d * DIM + t + 256] = f2bf(a1);
}

// ---------- small fp32 tiled GEMM: C[M,N] = (A[M,K] @ W[N,K]^T + bias) * scale ----------
#define BKT 32
#define LDT 68
__global__ __launch_bounds__(256)
void gemm_bt_f32(const float* __restrict__ A, const float* __restrict__ W,
                 const float* __restrict__ bias, float* __restrict__ Co,
                 int M, int N, int K, float out_scale)
{
    __shared__ float As[BKT * LDT];
    __shared__ float Ws[BKT * LDT];
    const int tid = threadIdx.x;
    const int m0 = blockIdx.y << 6, n0 = blockIdx.x << 6;
    const int tx = tid & 15, ty = tid >> 4;
    float acc[4][4] = {};
    for (int k0 = 0; k0 < K; k0 += BKT) {
        #pragma unroll
        for (int i = 0; i < 2; i++) {
            int slot = tid + (i << 8);
            int r = slot >> 3, kq = slot & 7;
            float4 v = *(const float4*)(A + (size_t)(m0 + r) * K + k0 + (kq << 2));
            As[(kq*4+0)*LDT + r] = v.x; As[(kq*4+1)*LDT + r] = v.y;
            As[(kq*4+2)*LDT + r] = v.z; As[(kq*4+3)*LDT + r] = v.w;
            float4 w = *(const float4*)(W + (size_t)(n0 + r) * K + k0 + (kq << 2));
            Ws[(kq*4+0)*LDT + r] = w.x; Ws[(kq*4+1)*LDT + r] = w.y;
            Ws[(kq*4+2)*LDT + r] = w.z; Ws[(kq*4+3)*LDT + r] = w.w;
        }
        __syncthreads();
        #pragma unroll
        for (int kk = 0; kk < BKT; kk++) {
            float4 a = *(const float4*)(As + kk*LDT + ty*4);
            float4 w = *(const float4*)(Ws + kk*LDT + tx*4);
            acc[0][0] += a.x*w.x; acc[0][1] += a.x*w.y; acc[0][2] += a.x*w.z; acc[0][3] += a.x*w.w;
            acc[1][0] += a.y*w.x; acc[1][1] += a.y*w.y; acc[1][2] += a.y*w.z; acc[1][3] += a.y*w.w;
            acc[2][0] += a.z*w.x; acc[2][1] += a.z*w.y; acc[2][2] += a.z*w.z; acc[2][3] += a.z*w.w;
            acc[3][0] += a.w*w.x; acc[3][1] += a.w*w.y; acc[3][2] += a.w*w.z; acc[3][3] += a.w*w.w;
        }
        __syncthreads();
    }
    #pragma unroll
    for (int i = 0; i < 4; i++) {
        int mr = m0 + ty*4 + i;
        #pragma unroll
        for (int j = 0; j < 4; j++) {
            int n = n0 + tx*4 + j;
            float v = acc[i][j];
            if (bias) v += bias[n];
            Co[(size_t)mr * N + n] = v * out_scale;
        }
    }
}

// ---------- small fp32 GEMM, B NOT transposed: C[M,N] = A[M,K] @ W[K,N] ----------
__global__ __launch_bounds__(256)
void gemm_nt_f32(const float* __restrict__ A, const float* __restrict__ W,
                 float* __restrict__ Co, int M, int N, int K)
{
    __shared__ float As[BKT * LDT];
    __shared__ float Ws[BKT * LDT];
    const int tid = threadIdx.x;
    const int m0 = blockIdx.y << 6, n0 = blockIdx.x << 6;
    const int tx = tid & 15, ty = tid >> 4;
    float acc[4][4] = {};
    for (int k0 = 0; k0 < K; k0 += BKT) {
        #pragma unroll
        for (int i = 0; i < 2; i++) {
            int slot = tid + (i << 8);
            int r = slot >> 3, kq = slot & 7;
            float4 v = *(const float4*)(A + (size_t)(m0 + r) * K + k0 + (kq << 2));
            As[(kq*4+0)*LDT + r] = v.x; As[(kq*4+1)*LDT + r] = v.y;
            As[(kq*4+2)*LDT + r] = v.z; As[(kq*4+3)*LDT + r] = v.w;
            int kr = slot >> 4, c4 = slot & 15;
            *(float4*)(Ws + kr*LDT + c4*4) =
                *(const float4*)(W + (size_t)(k0 + kr) * N + n0 + (c4 << 2));
        }
        __syncthreads();
        #pragma unroll
        for (int kk = 0; kk < BKT; kk++) {
            float4 a = *(const float4*)(As + kk*LDT + ty*4);
            float4 w = *(const float4*)(Ws + kk*LDT + tx*4);
            acc[0][0] += a.x*w.x; acc[0][1] += a.x*w.y; acc[0][2] += a.x*w.z; acc[0][3] += a.x*w.w;
            acc[1][0] += a.y*w.x; acc[1][1] += a.y*w.y; acc[1][2] += a.y*w.z; acc[1][3] += a.y*w.w;
            acc[2][0] += a.z*w.x; acc[2][1] += a.z*w.y; acc[2][2] += a.z*w.z; acc[2][3] += a.z*w.w;
            acc[3][0] += a.w*w.x; acc[3][1] += a.w*w.y; acc[3][2] += a.w*w.z; acc[3][3] += a.w*w.w;
        }
        __syncthreads();
    }
    #pragma unroll
    for (int i = 0; i < 4; i++) {
        int mr = m0 + ty*4 + i;
        #pragma unroll
        for (int j = 0; j < 4; j++)
            Co[(size_t)mr * N + n0 + tx*4 + j] = acc[i][j];
    }
}

// ---------- self-attention over the 12-layer axis, one block per batch ----------
__global__ __launch_bounds__(256)
void attn_kernel(const float* __restrict__ qkv, float* __restrict__ ao)
{
    __shared__ float lq[L_IMG * DIM];
    __shared__ float lk[L_IMG * DIM];
    __shared__ float sc[L_IMG * L_IMG];
    __shared__ float sa[L_IMG * L_IMG];
    const int b = blockIdx.x, tid = threadIdx.x;
    for (int i = 0; i < 6; i++) {
        int slot = tid + (i << 8);
        int l = slot >> 7, e4 = slot & 127;
        const float* row = qkv + (size_t)(l * BATCH + b) * 1536;
        *(float4*)(lq + l*DIM + e4*4) = *(const float4*)(row + e4*4);
        *(float4*)(lk + l*DIM + e4*4) = *(const float4*)(row + DIM + e4*4);
    }
    __syncthreads();
    if (tid < 144) {
        int l = tid / 12, m = tid % 12;
        float a = 0.f;
        for (int d4 = 0; d4 < 128; d4++) {
            float4 q = *(const float4*)(lq + l*DIM + d4*4);
            float4 k = *(const float4*)(lk + m*DIM + d4*4);
            a += q.x*k.x + q.y*k.y + q.z*k.z + q.w*k.w;
        }
        sc[tid] = a * SCALEF;
    }
    __syncthreads();
    if (tid < 12) {
        float mx = -1e30f;
        for (int m = 0; m < 12; m++) mx = fmaxf(mx, sc[tid*12 + m]);
        float e[12], s = 0.f;
        for (int m = 0; m < 12; m++) { e[m] = __expf(sc[tid*12 + m] - mx); s += e[m]; }
        float inv = 1.f / s;
        for (int m = 0; m < 12; m++) sa[tid*12 + m] = e[m] * inv;
    }
    __syncthreads();
    for (int i = 0; i < 2; i++) {
        int e = tid + (i << 8);
        float vv[12];
        #pragma unroll
        for (int m = 0; m < 12; m++)
            vv[m] = qkv[(size_t)(m * BATCH + b) * 1536 + 1024 + e];
        #pragma unroll
        for (int l = 0; l < 12; l++) {
            float a = 0.f;
            #pragma unroll
            for (int m = 0; m < 12; m++) a += sa[l*12 + m] * vv[m];
            ao[(size_t)(l * BATCH + b) * DIM + e] = a;
        }
    }
}

// ---------- normalize image features (xs layer 11) ----------
__global__ __launch_bounds__(256)
void img_kernel(const float* __restrict__ xs, float* __restrict__ imgn)
{
    __shared__ float red[256];
    const int b = blockIdx.x, tid = threadIdx.x;
    const float* row = xs + (size_t)(11 * BATCH + b) * DIM;
    float v0 = row[tid], v1 = row[tid + 256];
    red[tid] = v0*v0 + v1*v1;
    __syncthreads();
    for (int s = 128; s > 0; s >>= 1) {
        if (tid < s) red[tid] += red[tid + s];
        __syncthreads();
    }
    float inv = rsqrtf(red[0]);
    imgn[b*DIM + tid]       = v0 * inv;
    imgn[b*DIM + tid + 256] = v1 * inv;
}

// ---------- q2k fp32 [12,64,512] -> q2pb bf16 [64*16, 512], l>=12 zero ----------
__global__ __launch_bounds__(256)
void build_q2p(const float* __restrict__ q2s, unsigned short* __restrict__ q2pb)
{
    const int l = blockIdx.x, b = blockIdx.y, t = threadIdx.x;
    int d0 = t * 2;
    unsigned int o = 0;
    if (l < 12) {
        float2 v = *(const float2*)(q2s + (size_t)(l * BATCH + b) * DIM + d0);
        o = (unsigned int)f2bf(v.x) | ((unsigned int)f2bf(v.y) << 16);
    }
    ((unsigned int*)q2pb)[(size_t)(b * 16 + l) * 256 + t] = o;
}

// ---------- MFMA GEMM: C[M,N] = A[M,K]@W[N,K]^T + bias ; 128x128 tile, BK=32 ----------
// Async global_load_lds staging (linear LDS dest, inverse-swizzled global source,
// swizzled ds_read). Double-buffered, one barrier per iteration.
template<typename OutT>
__global__ __launch_bounds__(256, 4)
void gemm_mfma(const unsigned short* __restrict__ A, const unsigned short* __restrict__ W,
               const float* __restrict__ bias, OutT* __restrict__ Co,
               int M, int N, float scale)
{
    const int K = DIM;
    __shared__ __align__(16) unsigned short AsBuf[2][128 * 32];
    __shared__ __align__(16) unsigned short WsBuf[2][128 * 32];
    const int m0 = blockIdx.y << 7, n0 = blockIdx.x << 7;
    const int tid = threadIdx.x;
    const int w = tid >> 6, lane = tid & 63;
    const int mt0 = (w & 1) * 4, nt0 = (w >> 1) * 4;
    const int r16 = lane & 15, kq = lane >> 4;
    const int row0 = (w << 5) + (lane >> 2), row1 = row0 + 16;
    const int sc0 = ((lane & 3) ^ ((row0 >> 1) & 3)) << 3;
    const int sc1 = ((lane & 3) ^ ((row1 >> 1) & 3)) << 3;
    const unsigned short* gA0 = A + (size_t)(m0 + row0) * K + sc0;
    const unsigned short* gA1 = A + (size_t)(m0 + row1) * K + sc1;
    const unsigned short* gW0 = W + (size_t)(n0 + row0) * K + sc0;
    const unsigned short* gW1 = W + (size_t)(n0 + row1) * K + sc1;
    const int lw = w << 10;
    int offa[4], offb[4];
    #pragma unroll
    for (int i = 0; i < 4; i++) {
        offa[i] = swz((mt0 + i) * 16 + r16, kq);
        offb[i] = swz((nt0 + i) * 16 + r16, kq);
    }
    f32x4 acc[4][4] = {};

    gload16(gA0, AsBuf[0] + lw);
    gload16(gA1, AsBuf[0] + lw + 512);
    gload16(gW0, WsBuf[0] + lw);
    gload16(gW1, WsBuf[0] + lw + 512);
    __syncthreads();

    #pragma unroll
    for (int t = 0; t < 16; t++) {
        const int cur = t & 1, nxt = cur ^ 1;
        if (t < 15) {
            const int ko = (t + 1) << 5;
            gload16(gA0 + ko, AsBuf[nxt] + lw);
            gload16(gA1 + ko, AsBuf[nxt] + lw + 512);
            gload16(gW0 + ko, WsBuf[nxt] + lw);
            gload16(gW1 + ko, WsBuf[nxt] + lw + 512);
        }
        bf16x8 af[4], bfr[4];
        #pragma unroll
        for (int i = 0; i < 4; i++) {
            af[i]  = *(const bf16x8*)(AsBuf[cur] + offa[i]);
            bfr[i] = *(const bf16x8*)(WsBuf[cur] + offb[i]);
        }
        #pragma unroll
        for (int i = 0; i < 4; i++)
            #pragma unroll
            for (int j = 0; j < 4; j++)
                acc[i][j] = __builtin_amdgcn_mfma_f32_16x16x32_bf16(af[i], bfr[j], acc[i][j], 0, 0, 0);
        if (t < 15) __syncthreads();
    }
    const int rbase = (lane >> 4) * 4;
    #pragma unroll
    for (int i = 0; i < 4; i++)
        #pragma unroll
        for (int j = 0; j < 4; j++) {
            int gcol = n0 + (nt0 + j) * 16 + r16;
            float bv = bias ? bias[gcol] : 0.f;
            #pragma unroll
            for (int r = 0; r < 4; r++) {
                int grow = m0 + (mt0 + i) * 16 + rbase + r;
                storeo(Co + (size_t)grow * N + gcol, acc[i][j][r] * scale + bv);
            }
        }
}

// ---------- fused scores + softmax(m) + sum_l: one block = (class c, 8 batches) ----------
// K-source is tfeb DIRECTLY (cWk folded into the query side; k-bias cancels in softmax).
// Async global_load_lds staging; XCD-grouped 1-D grid (8 bg-blocks of a class share an XCD).
__global__ __launch_bounds__(256, 5)
void fused_scores(const unsigned short* __restrict__ q2pb, const unsigned short* __restrict__ k2,
                  float* __restrict__ wout)
{
    __shared__ __align__(16) unsigned short AsBuf[2][128 * 32];  // 2 x 8192 B
    __shared__ __align__(16) unsigned short KsBuf[2][96 * 32];   // 2 x 6144 B
    const int bid = blockIdx.x;
    const int g = bid >> 6, r = bid & 63;
    const int c = g * 8 + (r & 7), bg = r >> 3;
    const int tid = threadIdx.x;
    const int m0 = bg << 7;
    const int w = tid >> 6, lane = tid & 63;
    const int mt0 = w * 2;
    const int r16 = lane & 15, kq = lane >> 4;
    const size_t kb = (size_t)c * NTM * DIM;
    const int row0 = (w << 5) + (lane >> 2), row1 = row0 + 16;
    const int sc0 = ((lane & 3) ^ ((row0 >> 1) & 3)) << 3;
    const int sc1 = ((lane & 3) ^ ((row1 >> 1) & 3)) << 3;
    const unsigned short* gA0 = q2pb + (size_t)(m0 + row0) * DIM + sc0;
    const unsigned short* gA1 = q2pb + (size_t)(m0 + row1) * DIM + sc1;
    const unsigned short* gK0 = k2 + kb + (size_t)row0 * DIM + sc0;
    const unsigned short* gK1 = k2 + kb + (size_t)row1 * DIM + sc1;
    const bool kw = (w < 3);
    const int lw = w << 10;
    int offa[2], offk[6];
    #pragma unroll
    for (int i = 0; i < 2; i++) offa[i] = swz((mt0 + i) * 16 + r16, kq);
    #pragma unroll
    for (int j = 0; j < 6; j++) offk[j] = swz(j * 16 + r16, kq);
    f32x4 acc[2][6] = {};

    gload16(gA0, AsBuf[0] + lw);
    gload16(gA1, AsBuf[0] + lw + 512);
    if (kw) {
        gload16(gK0, KsBuf[0] + lw);
        gload16(gK1, KsBuf[0] + lw + 512);
    }
    __syncthreads();

    #pragma unroll
    for (int t = 0; t < 16; t++) {
        const int cur = t & 1, nxt = cur ^ 1;
        if (t < 15) {
            const int ko = (t + 1) << 5;
            gload16(gA0 + ko, AsBuf[nxt] + lw);
            gload16(gA1 + ko, AsBuf[nxt] + lw + 512);
            if (kw) {
                gload16(gK0 + ko, KsBuf[nxt] + lw);
                gload16(gK1 + ko, KsBuf[nxt] + lw + 512);
            }
        }
        bf16x8 af[2], bfr[6];
        #pragma unroll
        for (int i = 0; i < 2; i++)
            af[i] = *(const bf16x8*)(AsBuf[cur] + offa[i]);
        #pragma unroll
        for (int j = 0; j < 6; j++)
            bfr[j] = *(const bf16x8*)(KsBuf[cur] + offk[j]);
        __builtin_amdgcn_s_setprio(1);
        #pragma unroll
        for (int j = 0; j < 6; j++) {
            acc[0][j] = __builtin_amdgcn_mfma_f32_16x16x32_bf16(af[0], bfr[j], acc[0][j], 0, 0, 0);
            acc[1][j] = __builtin_amdgcn_mfma_f32_16x16x32_bf16(af[1], bfr[j], acc[1][j], 0, 0, 0);
        }
        __builtin_amdgcn_s_setprio(0);
        if (t < 15) __syncthreads();
    }

    // in-register softmax over m (12 values per (row,t), split across lane pair lane^8)
    #pragma unroll
    for (int i = 0; i < 2; i++) {
        #pragma unroll
        for (int rr = 0; rr < 4; rr++) {
            float v0 = acc[i][0][rr], v1 = acc[i][1][rr], v2 = acc[i][2][rr];
            float v3 = acc[i][3][rr], v4 = acc[i][4][rr], v5 = acc[i][5][rr];
            float mx = fmaxf(fmaxf(fmaxf(v0, v1), fmaxf(v2, v3)), fmaxf(v4, v5));
            mx = fmaxf(mx, __shfl_xor(mx, 8, 64));
            float e0 = __expf(v0 - mx), e1 = __expf(v1 - mx), e2 = __expf(v2 - mx);
            float e3 = __expf(v3 - mx), e4 = __expf(v4 - mx), e5 = __expf(v5 - mx);
            float s = e0 + e1 + e2 + e3 + e4 + e5;
            s += __shfl_xor(s, 8, 64);
            float inv = 1.f / (96.f * s);
            acc[i][0][rr] = e0 * inv; acc[i][1][rr] = e1 * inv; acc[i][2][rr] = e2 * inv;
            acc[i][3][rr] = e3 * inv; acc[i][4][rr] = e4 * inv; acc[i][5][rr] = e5 * inv;
        }
    }

    // sum over l: in-lane over 4 rows (groups 0..2 = l 0..11; group 3 = pad),
    // then across row-groups via shfl_xor(16/32).
    const bool contrib = (lane >> 4) < 3;
    #pragma unroll
    for (int i = 0; i < 2; i++) {
        float s6[6];
        #pragma unroll
        for (int j = 0; j < 6; j++) {
            float t = contrib ? (acc[i][j][0] + acc[i][j][1] + acc[i][j][2] + acc[i][j][3]) : 0.f;
            t += __shfl_xor(t, 16, 64);
            t += __shfl_xor(t, 32, 64);
            s6[j] = t;
        }
        if (lane < 16) {
            const int b = bg * 8 + mt0 + i;
            float* dst = wout + ((size_t)(b * NCLS + c)) * NTM;
            #pragma unroll
            for (int j = 0; j < 6; j++)
                dst[j * 16 + r16] = s6[j];
        }
    }
}

// ---------- ctxraw[b,c,:] = sum_tm w[b,c,tm] * tfeb[c,tm,:]  (bf16 out) ----------
// One block = (class c, 16 batches). XCD-grouped 1-D grid: the 4 bg-blocks of a
// class land on the same XCD (idx%8 == c%8), so the 98 KB tfeb class block is
// HBM-fetched once then L2-served.
__global__ __launch_bounds__(256)
void ctx_kernel(const float* __restrict__ wbuf, const unsigned short* __restrict__ tfeb,
                unsigned short* __restrict__ ctxraw)
{
    __shared__ float ws[16 * NTM];
    const int bid = blockIdx.x;
    const int g = bid >> 5, r = bid & 31;
    const int c = g * 8 + (r & 7), bg = r >> 3;
    const int tid = threadIdx.x;
    for (int idx = tid; idx < 16 * NTM; idx += 256) {
        int bl = idx / NTM, tm = idx - bl * NTM;
        ws[idx] = wbuf[((size_t)((bg * 16 + bl) * NCLS + c)) * NTM + tm];
    }
    __syncthreads();
    float a0[16] = {}, a1[16] = {};
    const unsigned int* vrow = (const unsigned int*)(tfeb + (size_t)c * NTM * DIM) + tid;
    for (int tm = 0; tm < NTM; tm++) {
        unsigned int u = vrow[tm * 256];
        float vx = __uint_as_float(u << 16);
        float vy = __uint_as_float(u & 0xFFFF0000u);
        #pragma unroll
        for (int bl = 0; bl < 16; bl++) {
            float wv = ws[bl * NTM + tm];
            a0[bl] += wv * vx; a1[bl] += wv * vy;
        }
    }
    #pragma unroll
    for (int bl = 0; bl < 16; bl++) {
        int b = bg * 16 + bl;
        unsigned int o = (unsigned int)f2bf(a0[bl]) | ((unsigned int)f2bf(a1[bl]) << 16);
        ((unsigned int*)ctxraw)[(size_t)(b * NCLS + c) * 256 + tid] = o;
    }
}

// ---------- n2[b,d] = sum_c txt[b,c,d]^2 ----------
__global__ __launch_bounds__(256)
void n2_kernel(const unsigned short* __restrict__ txt, float* __restrict__ n2)
{
    const int b = blockIdx.x, cg = blockIdx.y, t = threadIdx.x;
    float a0 = 0.f, a1 = 0.f;
    const unsigned int* p = (const unsigned int*)txt + ((size_t)(b * NCLS + cg * 125)) * 256 + t;
    for (int c = 0; c < 125; c++) {
        unsigned int u = p[c * 256];
        float vx = __uint_as_float(u << 16);
        float vy = __uint_as_float(u & 0xFFFF0000u);
        a0 += vx * vx; a1 += vy * vy;
    }
    atomicAdd(&n2[b * DIM + t * 2], a0);
    atomicAdd(&n2[b * DIM + t * 2 + 1], a1);
}

// ---------- logits[b,c] = exp(ls) * sum_d imgn[b,d]/sqrt(n2[b,d]) * txt[b,c,d] ----------
__global__ __launch_bounds__(256)
void logits_kernel(const unsigned short* __restrict__ txt, const float* __restrict__ imgn,
                   const float* __restrict__ n2, const float* __restrict__ logit_scale,
                   float* __restrict__ out)
{
    __shared__ float lu[DIM];
    const int b = blockIdx.y, cg = blockIdx.x, tid = threadIdx.x;
    float els = expf(logit_scale[0]);
    lu[tid]       = els * imgn[b*DIM + tid]       * rsqrtf(n2[b*DIM + tid]);
    lu[tid + 256] = els * imgn[b*DIM + tid + 256] * rsqrtf(n2[b*DIM + tid + 256]);
    __syncthreads();
    int wave = tid >> 6, lane = tid & 63;
    int c = (cg << 2) + wave;
    const unsigned short* row = txt + (size_t)(b * NCLS + c) * DIM;
    ushort4 p0 = ((const ushort4*)row)[lane*2];
    ushort4 p1 = ((const ushort4*)row)[lane*2 + 1];
    int d0 = lane * 8;
    float s = bf2f(p0.x)*lu[d0]   + bf2f(p0.y)*lu[d0+1] + bf2f(p0.z)*lu[d0+2] + bf2f(p0.w)*lu[d0+3]
            + bf2f(p1.x)*lu[d0+4] + bf2f(p1.y)*lu[d0+5] + bf2f(p1.z)*lu[d0+6] + bf2f(p1.w)*lu[d0+7];
    #pragma unroll
    for (int off = 32; off > 0; off >>= 1) s += __shfl_down(s, off, 64);
    if (lane == 0) out[b*NCLS + c] = s;
}

extern "C" void kernel_launch(void* const* d_in, const int* in_sizes, int n_in,
                              void* d_out, int out_size, void* d_ws, size_t ws_size,
                              hipStream_t stream)
{
    const float* x   = (const float*)d_in[0];
    const float* tfe = (const float*)d_in[1];
    const float* siw = (const float*)d_in[2];
    const float* sib = (const float*)d_in[3];
    const float* sow = (const float*)d_in[4];
    const float* sob = (const float*)d_in[5];
    const float* ciw = (const float*)d_in[6];
    const float* cib = (const float*)d_in[7];
    const float* cow = (const float*)d_in[8];
    const float* cob = (const float*)d_in[9];
    const float* ls  = (const float*)d_in[10];
    float* out = (float*)d_out;

    char* p = (char*)d_ws;
    auto alloc = [&](size_t bytes) { char* r = p; p += (bytes + 255) & ~255ull; return r; };
    unsigned short* tfeb   = (unsigned short*)alloc((size_t)49152000 * 2);   // 98.3 MB
    unsigned short* ctxraw = (unsigned short*)alloc((size_t)BATCH * NCLS * DIM * 2);  // 65.5 MB
    float* wbuf            = (float*)alloc((size_t)BATCH * NCLS * NTM * 4);  // 24.6 MB
    float* qkv             = (float*)alloc((size_t)768 * 1536 * 4);
    float* ao              = (float*)alloc((size_t)768 * DIM * 4);
    float* xs              = (float*)alloc((size_t)768 * DIM * 4);
    float* q2s             = (float*)alloc((size_t)768 * DIM * 4);
    float* q2k             = (float*)alloc((size_t)768 * DIM * 4);
    unsigned short* q2pb   = (unsigned short*)alloc((size_t)1024 * DIM * 2);
    unsigned short* Wvob   = (unsigned short*)alloc((size_t)DIM * DIM * 2);
    float* bvo             = (float*)alloc(DIM * 4);
    float* n2              = (float*)alloc(BATCH * DIM * 4);
    float* imgn            = (float*)alloc(BATCH * DIM * 4);
    unsigned short* txt    = tfeb;   // alias: tfeb dead after ctx_kernel; txt written after

    hipMemsetAsync(n2, 0, BATCH * DIM * 4, stream);

    // weight/text prep
    f2bf_kernel<<<48000, 256, 0, stream>>>(tfe, tfeb, 49152000);
    fold_wvo<<<512, 256, 0, stream>>>(cow, ciw + 1024*512, cib + 1024, cob, Wvob, bvo);

    // self-attn head (fp32, small)
    gemm_bt_f32<<<dim3(24, 12), 256, 0, stream>>>(x, siw, sib, qkv, 768, 1536, 512, 1.f);
    attn_kernel<<<64, 256, 0, stream>>>(qkv, ao);
    gemm_bt_f32<<<dim3(8, 12), 256, 0, stream>>>(ao, sow, sob, xs, 768, 512, 512, 1.f);
    img_kernel<<<64, 256, 0, stream>>>(xs, imgn);
    gemm_bt_f32<<<dim3(8, 12), 256, 0, stream>>>(xs, ciw, cib, q2s, 768, 512, 512, SCALEF);
    // fold cWk into query: q2k = q2s @ cWk   (k-bias cancels in softmax over m)
    gemm_nt_f32<<<dim3(8, 12), 256, 0, stream>>>(q2s, ciw + 512*512, q2k, 768, 512, 512);
    build_q2p<<<dim3(16, 64), 256, 0, stream>>>(q2k, q2pb);

    // fused scores+softmax -> w[b,c,96]  (K = raw text features; XCD-grouped 1-D grid)
    fused_scores<<<8000, 256, 0, stream>>>(q2pb, tfeb, wbuf);

    // ctxraw = w @ tf  (value projection deferred past the template/layer average)
    ctx_kernel<<<4000, 256, 0, stream>>>(wbuf, tfeb, ctxraw);

    // txt = ctxraw @ Wvob^T + (bvo + cob)   (MFMA, 64000 rows)
    gemm_mfma<unsigned short><<<dim3(4, 500), 256, 0, stream>>>(
        ctxraw, Wvob, bvo, txt, 64000, 512, 1.f);

    // norms and logits
    n2_kernel<<<dim3(64, 8), 256, 0, stream>>>(txt, n2);
    logits_kernel<<<dim3(250, 64), 256, 0, stream>>>(txt, imgn, n2, ls, out);
}

// Round 8
// 762.728 us; speedup vs baseline: 1.5184x; 1.0398x over previous
//
#include <hip/hip_runtime.h>

#define L_IMG 12
#define BATCH 64
#define NCLS  1000
#define DIM   512
#define NTM   96
#define SCALEF 0.044194173824159216f   // 1/sqrt(512)

typedef __attribute__((ext_vector_type(8))) short bf16x8;
typedef __attribute__((ext_vector_type(4))) float f32x4;

// ---------- bf16 helpers ----------
__device__ __forceinline__ float bf2f(unsigned short u) {
    return __uint_as_float(((unsigned int)u) << 16);
}
__device__ __forceinline__ unsigned short f2bf(float f) {
    unsigned int u = __float_as_uint(f);
    u += 0x7FFFu + ((u >> 16) & 1u);
    return (unsigned short)(u >> 16);
}
__device__ __forceinline__ void storeo(float* p, float v) { *p = v; }
__device__ __forceinline__ void storeo(unsigned short* p, float v) { *p = f2bf(v); }

// XOR-swizzled LDS offset (shorts) for [row][32-short] tiles: 16B unit u ^= (row>>1)&3.
__device__ __forceinline__ int swz(int row, int u) {
    return (row << 5) + ((u ^ ((row >> 1) & 3)) << 3);
}

// async global->LDS, 16 B per lane; LDS dest = wave-uniform base + lane*16 (linear).
// Swizzle achieved by inverse-permuting the per-lane GLOBAL source (rule #21).
__device__ __forceinline__ void gload16(const unsigned short* g, unsigned short* l) {
    __builtin_amdgcn_global_load_lds(
        (const __attribute__((address_space(1))) void*)g,
        (__attribute__((address_space(3))) void*)l, 16, 0, 0);
}

// ---------- fp32 -> bf16 convert (n multiple of 4) ----------
__global__ __launch_bounds__(256)
void f2bf_kernel(const float* __restrict__ in, unsigned short* __restrict__ out, int n)
{
    int i = (blockIdx.x * 256 + threadIdx.x) * 4;
    if (i < n) {
        float4 v = *(const float4*)(in + i);
        ushort4 o;
        o.x = f2bf(v.x); o.y = f2bf(v.y); o.z = f2bf(v.z); o.w = f2bf(v.w);
        *(ushort4*)(out + i) = o;
    }
}

// ---------- Wvo[d,k] = sum_e cow[d,e]*cWv[e,k] (bf16), bvo[d] = cow[d,:].cbv + cob[d] ----------
__global__ __launch_bounds__(256)
void fold_wvo(const float* __restrict__ cow, const float* __restrict__ cWv,
              const float* __restrict__ cbv, const float* __restrict__ cob,
              unsigned short* __restrict__ Wvob, float* __restrict__ bvo)
{
    __shared__ float crow[DIM];
    __shared__ float red[256];
    const int d = blockIdx.x, t = threadIdx.x;
    float c0 = cow[d * DIM + t], c1 = cow[d * DIM + t + 256];
    crow[t] = c0; crow[t + 256] = c1;
    red[t] = c0 * cbv[t] + c1 * cbv[t + 256];
    __syncthreads();
    for (int s = 128; s > 0; s >>= 1) {
        if (t < s) red[t] += red[t + s];
        __syncthreads();
    }
    if (t == 0) bvo[d] = red[0] + cob[d];
    float a0 = 0.f, a1 = 0.f;
    for (int e = 0; e < DIM; e++) {
        float ce = crow[e];
        a0 += ce * cWv[e * DIM + t];
        a1 += ce * cWv[e * DIM + t + 256];
    }
    Wvob[d * DIM + t]       = f2bf(a0);
    Wvob[d * DIM + t + 256] = f2bf(a1);
}

// ---------- small fp32 tiled GEMM: C[M,N] = (A[M,K] @ W[N,K]^T + bias) * scale ----------
#define BKT 32
#define LDT 68
__global__ __launch_bounds__(256)
void gemm_bt_f32(const float* __restrict__ A, const float* __restrict__ W,
                 const float* __restrict__ bias, float* __restrict__ Co,
                 int M, int N, int K, float out_scale)
{
    __shared__ float As[BKT * LDT];
    __shared__ float Ws[BKT * LDT];
    const int tid = threadIdx.x;
    const int m0 = blockIdx.y << 6, n0 = blockIdx.x << 6;
    const int tx = tid & 15, ty = tid >> 4;
    float acc[4][4] = {};
    for (int k0 = 0; k0 < K; k0 += BKT) {
        #pragma unroll
        for (int i = 0; i < 2; i++) {
            int slot = tid + (i << 8);
            int r = slot >> 3, kq = slot & 7;
            float4 v = *(const float4*)(A + (size_t)(m0 + r) * K + k0 + (kq << 2));
            As[(kq*4+0)*LDT + r] = v.x; As[(kq*4+1)*LDT + r] = v.y;
            As[(kq*4+2)*LDT + r] = v.z; As[(kq*4+3)*LDT + r] = v.w;
            float4 w = *(const float4*)(W + (size_t)(n0 + r) * K + k0 + (kq << 2));
            Ws[(kq*4+0)*LDT + r] = w.x; Ws[(kq*4+1)*LDT + r] = w.y;
            Ws[(kq*4+2)*LDT + r] = w.z; Ws[(kq*4+3)*LDT + r] = w.w;
        }
        __syncthreads();
        #pragma unroll
        for (int kk = 0; kk < BKT; kk++) {
            float4 a = *(const float4*)(As + kk*LDT + ty*4);
            float4 w = *(const float4*)(Ws + kk*LDT + tx*4);
            acc[0][0] += a.x*w.x; acc[0][1] += a.x*w.y; acc[0][2] += a.x*w.z; acc[0][3] += a.x*w.w;
            acc[1][0] += a.y*w.x; acc[1][1] += a.y*w.y; acc[1][2] += a.y*w.z; acc[1][3] += a.y*w.w;
            acc[2][0] += a.z*w.x; acc[2][1] += a.z*w.y; acc[2][2] += a.z*w.z; acc[2][3] += a.z*w.w;
            acc[3][0] += a.w*w.x; acc[3][1] += a.w*w.y; acc[3][2] += a.w*w.z; acc[3][3] += a.w*w.w;
        }
        __syncthreads();
    }
    #pragma unroll
    for (int i = 0; i < 4; i++) {
        int mr = m0 + ty*4 + i;
        #pragma unroll
        for (int j = 0; j < 4; j++) {
            int n = n0 + tx*4 + j;
            float v = acc[i][j];
            if (bias) v += bias[n];
            Co[(size_t)mr * N + n] = v * out_scale;
        }
    }
}

// ---------- small fp32 GEMM, B NOT transposed: C[M,N] = A[M,K] @ W[K,N] ----------
__global__ __launch_bounds__(256)
void gemm_nt_f32(const float* __restrict__ A, const float* __restrict__ W,
                 float* __restrict__ Co, int M, int N, int K)
{
    __shared__ float As[BKT * LDT];
    __shared__ float Ws[BKT * LDT];
    const int tid = threadIdx.x;
    const int m0 = blockIdx.y << 6, n0 = blockIdx.x << 6;
    const int tx = tid & 15, ty = tid >> 4;
    float acc[4][4] = {};
    for (int k0 = 0; k0 < K; k0 += BKT) {
        #pragma unroll
        for (int i = 0; i < 2; i++) {
            int slot = tid + (i << 8);
            int r = slot >> 3, kq = slot & 7;
            float4 v = *(const float4*)(A + (size_t)(m0 + r) * K + k0 + (kq << 2));
            As[(kq*4+0)*LDT + r] = v.x; As[(kq*4+1)*LDT + r] = v.y;
            As[(kq*4+2)*LDT + r] = v.z; As[(kq*4+3)*LDT + r] = v.w;
            int kr = slot >> 4, c4 = slot & 15;
            *(float4*)(Ws + kr*LDT + c4*4) =
                *(const float4*)(W + (size_t)(k0 + kr) * N + n0 + (c4 << 2));
        }
        __syncthreads();
        #pragma unroll
        for (int kk = 0; kk < BKT; kk++) {
            float4 a = *(const float4*)(As + kk*LDT + ty*4);
            float4 w = *(const float4*)(Ws + kk*LDT + tx*4);
            acc[0][0] += a.x*w.x; acc[0][1] += a.x*w.y; acc[0][2] += a.x*w.z; acc[0][3] += a.x*w.w;
            acc[1][0] += a.y*w.x; acc[1][1] += a.y*w.y; acc[1][2] += a.y*w.z; acc[1][3] += a.y*w.w;
            acc[2][0] += a.z*w.x; acc[2][1] += a.z*w.y; acc[2][2] += a.z*w.z; acc[2][3] += a.z*w.w;
            acc[3][0] += a.w*w.x; acc[3][1] += a.w*w.y; acc[3][2] += a.w*w.z; acc[3][3] += a.w*w.w;
        }
        __syncthreads();
    }
    #pragma unroll
    for (int i = 0; i < 4; i++) {
        int mr = m0 + ty*4 + i;
        #pragma unroll
        for (int j = 0; j < 4; j++)
            Co[(size_t)mr * N + n0 + tx*4 + j] = acc[i][j];
    }
}

// ---------- self-attention over the 12-layer axis, one block per batch ----------
__global__ __launch_bounds__(256)
void attn_kernel(const float* __restrict__ qkv, float* __restrict__ ao)
{
    __shared__ float lq[L_IMG * DIM];
    __shared__ float lk[L_IMG * DIM];
    __shared__ float sc[L_IMG * L_IMG];
    __shared__ float sa[L_IMG * L_IMG];
    const int b = blockIdx.x, tid = threadIdx.x;
    for (int i = 0; i < 6; i++) {
        int slot = tid + (i << 8);
        int l = slot >> 7, e4 = slot & 127;
        const float* row = qkv + (size_t)(l * BATCH + b) * 1536;
        *(float4*)(lq + l*DIM + e4*4) = *(const float4*)(row + e4*4);
        *(float4*)(lk + l*DIM + e4*4) = *(const float4*)(row + DIM + e4*4);
    }
    __syncthreads();
    if (tid < 144) {
        int l = tid / 12, m = tid % 12;
        float a = 0.f;
        for (int d4 = 0; d4 < 128; d4++) {
            float4 q = *(const float4*)(lq + l*DIM + d4*4);
            float4 k = *(const float4*)(lk + m*DIM + d4*4);
            a += q.x*k.x + q.y*k.y + q.z*k.z + q.w*k.w;
        }
        sc[tid] = a * SCALEF;
    }
    __syncthreads();
    if (tid < 12) {
        float mx = -1e30f;
        for (int m = 0; m < 12; m++) mx = fmaxf(mx, sc[tid*12 + m]);
        float e[12], s = 0.f;
        for (int m = 0; m < 12; m++) { e[m] = __expf(sc[tid*12 + m] - mx); s += e[m]; }
        float inv = 1.f / s;
        for (int m = 0; m < 12; m++) sa[tid*12 + m] = e[m] * inv;
    }
    __syncthreads();
    for (int i = 0; i < 2; i++) {
        int e = tid + (i << 8);
        float vv[12];
        #pragma unroll
        for (int m = 0; m < 12; m++)
            vv[m] = qkv[(size_t)(m * BATCH + b) * 1536 + 1024 + e];
        #pragma unroll
        for (int l = 0; l < 12; l++) {
            float a = 0.f;
            #pragma unroll
            for (int m = 0; m < 12; m++) a += sa[l*12 + m] * vv[m];
            ao[(size_t)(l * BATCH + b) * DIM + e] = a;
        }
    }
}

// ---------- normalize image features (xs layer 11) ----------
__global__ __launch_bounds__(256)
void img_kernel(const float* __restrict__ xs, float* __restrict__ imgn)
{
    __shared__ float red[256];
    const int b = blockIdx.x, tid = threadIdx.x;
    const float* row = xs + (size_t)(11 * BATCH + b) * DIM;
    float v0 = row[tid], v1 = row[tid + 256];
    red[tid] = v0*v0 + v1*v1;
    __syncthreads();
    for (int s = 128; s > 0; s >>= 1) {
        if (tid < s) red[tid] += red[tid + s];
        __syncthreads();
    }
    float inv = rsqrtf(red[0]);
    imgn[b*DIM + tid]       = v0 * inv;
    imgn[b*DIM + tid + 256] = v1 * inv;
}

// ---------- q2k fp32 [12,64,512] -> q2pb bf16 [64*16, 512], l>=12 zero ----------
__global__ __launch_bounds__(256)
void build_q2p(const float* __restrict__ q2s, unsigned short* __restrict__ q2pb)
{
    const int l = blockIdx.x, b = blockIdx.y, t = threadIdx.x;
    int d0 = t * 2;
    unsigned int o = 0;
    if (l < 12) {
        float2 v = *(const float2*)(q2s + (size_t)(l * BATCH + b) * DIM + d0);
        o = (unsigned int)f2bf(v.x) | ((unsigned int)f2bf(v.y) << 16);
    }
    ((unsigned int*)q2pb)[(size_t)(b * 16 + l) * 256 + t] = o;
}

// ---------- MFMA GEMM: C[M,N] = A[M,K]@W[N,K]^T + bias ; 128x128 tile, BK=32 ----------
// Async global_load_lds staging (linear LDS dest, inverse-swizzled global source,
// swizzled ds_read). Double-buffered, one barrier per iteration.
template<typename OutT>
__global__ __launch_bounds__(256, 4)
void gemm_mfma(const unsigned short* __restrict__ A, const unsigned short* __restrict__ W,
               const float* __restrict__ bias, OutT* __restrict__ Co,
               int M, int N, float scale)
{
    const int K = DIM;
    __shared__ __align__(16) unsigned short AsBuf[2][128 * 32];
    __shared__ __align__(16) unsigned short WsBuf[2][128 * 32];
    const int m0 = blockIdx.y << 7, n0 = blockIdx.x << 7;
    const int tid = threadIdx.x;
    const int w = tid >> 6, lane = tid & 63;
    const int mt0 = (w & 1) * 4, nt0 = (w >> 1) * 4;
    const int r16 = lane & 15, kq = lane >> 4;
    const int row0 = (w << 5) + (lane >> 2), row1 = row0 + 16;
    const int sc0 = ((lane & 3) ^ ((row0 >> 1) & 3)) << 3;
    const int sc1 = ((lane & 3) ^ ((row1 >> 1) & 3)) << 3;
    const unsigned short* gA0 = A + (size_t)(m0 + row0) * K + sc0;
    const unsigned short* gA1 = A + (size_t)(m0 + row1) * K + sc1;
    const unsigned short* gW0 = W + (size_t)(n0 + row0) * K + sc0;
    const unsigned short* gW1 = W + (size_t)(n0 + row1) * K + sc1;
    const int lw = w << 10;
    int offa[4], offb[4];
    #pragma unroll
    for (int i = 0; i < 4; i++) {
        offa[i] = swz((mt0 + i) * 16 + r16, kq);
        offb[i] = swz((nt0 + i) * 16 + r16, kq);
    }
    f32x4 acc[4][4] = {};

    gload16(gA0, AsBuf[0] + lw);
    gload16(gA1, AsBuf[0] + lw + 512);
    gload16(gW0, WsBuf[0] + lw);
    gload16(gW1, WsBuf[0] + lw + 512);
    __syncthreads();

    #pragma unroll
    for (int t = 0; t < 16; t++) {
        const int cur = t & 1, nxt = cur ^ 1;
        if (t < 15) {
            const int ko = (t + 1) << 5;
            gload16(gA0 + ko, AsBuf[nxt] + lw);
            gload16(gA1 + ko, AsBuf[nxt] + lw + 512);
            gload16(gW0 + ko, WsBuf[nxt] + lw);
            gload16(gW1 + ko, WsBuf[nxt] + lw + 512);
        }
        bf16x8 af[4], bfr[4];
        #pragma unroll
        for (int i = 0; i < 4; i++) {
            af[i]  = *(const bf16x8*)(AsBuf[cur] + offa[i]);
            bfr[i] = *(const bf16x8*)(WsBuf[cur] + offb[i]);
        }
        #pragma unroll
        for (int i = 0; i < 4; i++)
            #pragma unroll
            for (int j = 0; j < 4; j++)
                acc[i][j] = __builtin_amdgcn_mfma_f32_16x16x32_bf16(af[i], bfr[j], acc[i][j], 0, 0, 0);
        if (t < 15) __syncthreads();
    }
    const int rbase = (lane >> 4) * 4;
    #pragma unroll
    for (int i = 0; i < 4; i++)
        #pragma unroll
        for (int j = 0; j < 4; j++) {
            int gcol = n0 + (nt0 + j) * 16 + r16;
            float bv = bias ? bias[gcol] : 0.f;
            #pragma unroll
            for (int r = 0; r < 4; r++) {
                int grow = m0 + (mt0 + i) * 16 + rbase + r;
                storeo(Co + (size_t)grow * N + gcol, acc[i][j][r] * scale + bv);
            }
        }
}

// ---------- fused scores + softmax(m) + sum_l: one block = (class c, 16 batches) ----------
// Retiled so each wave owns 64 A-rows x 96 K-cols (acc[4][6]): K-frag reads amortize
// over 4 A-frags -> LDS cycles/MFMA drop 8.0 -> 5.0 (the measured bottleneck).
// K-source is tfeb directly (cWk folded into query; k-bias cancels in softmax).
// Async global_load_lds staging; XCD-grouped 1-D grid (4 bg-blocks of a class share an XCD).
__global__ __launch_bounds__(256, 3)
void fused_scores(const unsigned short* __restrict__ q2pb, const unsigned short* __restrict__ k2,
                  float* __restrict__ wout)
{
    __shared__ __align__(16) unsigned short AsBuf[2][256 * 32];  // 2 x 16384 B
    __shared__ __align__(16) unsigned short KsBuf[2][96 * 32];   // 2 x  6144 B
    const int bid = blockIdx.x;
    const int g = bid >> 5, r = bid & 31;
    const int c = g * 8 + (r & 7), bg = r >> 3;     // bg in 0..3, 16 batches each
    const int tid = threadIdx.x;
    const int m0 = bg << 8;
    const int w = tid >> 6, lane = tid & 63;
    const int r16 = lane & 15, kq = lane >> 4;
    const size_t kb = (size_t)c * NTM * DIM;
    const int arow = lane >> 2, aun = lane & 3;
    // A staging: wave w stages rows w*64 .. w*64+63 (4 issues x 16 rows)
    const unsigned short* gAs[4];
    #pragma unroll
    for (int s = 0; s < 4; s++) {
        int rw = (w << 6) + (s << 4) + arow;
        int scx = (aun ^ ((rw >> 1) & 3)) << 3;
        gAs[s] = q2pb + (size_t)(m0 + rw) * DIM + scx;
    }
    // K staging: waves 0..2 stage rows w*32 .. w*32+31 (2 issues)
    const int krow0 = (w << 5) + arow, krow1 = krow0 + 16;
    const int sk0 = (aun ^ ((krow0 >> 1) & 3)) << 3;
    const int sk1 = (aun ^ ((krow1 >> 1) & 3)) << 3;
    const unsigned short* gK0 = k2 + kb + (size_t)krow0 * DIM + sk0;
    const unsigned short* gK1 = k2 + kb + (size_t)krow1 * DIM + sk1;
    const bool kw = (w < 3);
    const int lwA = w << 11;   // wave-uniform A base (shorts): 64 rows * 32
    const int lwK = w << 10;   // wave-uniform K base (shorts): 32 rows * 32
    int offa[4], offk[6];
    #pragma unroll
    for (int i = 0; i < 4; i++) offa[i] = swz((w << 6) + i * 16 + r16, kq);
    #pragma unroll
    for (int j = 0; j < 6; j++) offk[j] = swz(j * 16 + r16, kq);
    f32x4 acc[4][6] = {};

    #pragma unroll
    for (int s = 0; s < 4; s++) gload16(gAs[s], AsBuf[0] + lwA + (s << 9));
    if (kw) {
        gload16(gK0, KsBuf[0] + lwK);
        gload16(gK1, KsBuf[0] + lwK + 512);
    }
    __syncthreads();

    #pragma unroll
    for (int t = 0; t < 16; t++) {
        const int cur = t & 1, nxt = cur ^ 1;
        if (t < 15) {
            const int ko = (t + 1) << 5;
            #pragma unroll
            for (int s = 0; s < 4; s++) gload16(gAs[s] + ko, AsBuf[nxt] + lwA + (s << 9));
            if (kw) {
                gload16(gK0 + ko, KsBuf[nxt] + lwK);
                gload16(gK1 + ko, KsBuf[nxt] + lwK + 512);
            }
        }
        bf16x8 af[4], bfr[6];
        #pragma unroll
        for (int i = 0; i < 4; i++)
            af[i] = *(const bf16x8*)(AsBuf[cur] + offa[i]);
        #pragma unroll
        for (int j = 0; j < 6; j++)
            bfr[j] = *(const bf16x8*)(KsBuf[cur] + offk[j]);
        __builtin_amdgcn_s_setprio(1);
        #pragma unroll
        for (int i = 0; i < 4; i++)
            #pragma unroll
            for (int j = 0; j < 6; j++)
                acc[i][j] = __builtin_amdgcn_mfma_f32_16x16x32_bf16(af[i], bfr[j], acc[i][j], 0, 0, 0);
        __builtin_amdgcn_s_setprio(0);
        if (t < 15) __syncthreads();
    }

    // in-register softmax over m (12 values per (row,t), split across lane pair lane^8)
    #pragma unroll
    for (int i = 0; i < 4; i++) {
        #pragma unroll
        for (int rr = 0; rr < 4; rr++) {
            float v0 = acc[i][0][rr], v1 = acc[i][1][rr], v2 = acc[i][2][rr];
            float v3 = acc[i][3][rr], v4 = acc[i][4][rr], v5 = acc[i][5][rr];
            float mx = fmaxf(fmaxf(fmaxf(v0, v1), fmaxf(v2, v3)), fmaxf(v4, v5));
            mx = fmaxf(mx, __shfl_xor(mx, 8, 64));
            float e0 = __expf(v0 - mx), e1 = __expf(v1 - mx), e2 = __expf(v2 - mx);
            float e3 = __expf(v3 - mx), e4 = __expf(v4 - mx), e5 = __expf(v5 - mx);
            float s = e0 + e1 + e2 + e3 + e4 + e5;
            s += __shfl_xor(s, 8, 64);
            float inv = 1.f / (96.f * s);
            acc[i][0][rr] = e0 * inv; acc[i][1][rr] = e1 * inv; acc[i][2][rr] = e2 * inv;
            acc[i][3][rr] = e3 * inv; acc[i][4][rr] = e4 * inv; acc[i][5][rr] = e5 * inv;
        }
    }

    // sum over l: in-lane over 4 rows (groups 0..2 = l 0..11; group 3 = pad),
    // then across row-groups via shfl_xor(16/32).
    const bool contrib = (lane >> 4) < 3;
    #pragma unroll
    for (int i = 0; i < 4; i++) {
        float s6[6];
        #pragma unroll
        for (int j = 0; j < 6; j++) {
            float t = contrib ? (acc[i][j][0] + acc[i][j][1] + acc[i][j][2] + acc[i][j][3]) : 0.f;
            t += __shfl_xor(t, 16, 64);
            t += __shfl_xor(t, 32, 64);
            s6[j] = t;
        }
        if (lane < 16) {
            const int b = bg * 16 + (w << 2) + i;
            float* dst = wout + ((size_t)(b * NCLS + c)) * NTM;
            #pragma unroll
            for (int j = 0; j < 6; j++)
                dst[j * 16 + r16] = s6[j];
        }
    }
}

// ---------- ctxraw[b,c,:] = sum_tm w[b,c,tm] * tfeb[c,tm,:]  (bf16 out) ----------
// ws stored TRANSPOSED (ws[tm*16+bl]) so the 16 per-tm weights load as 4 float4
// broadcasts instead of 16 scalar LDS reads; tm loop unrolled to pipeline loads.
__global__ __launch_bounds__(256)
void ctx_kernel(const float* __restrict__ wbuf, const unsigned short* __restrict__ tfeb,
                unsigned short* __restrict__ ctxraw)
{
    __shared__ float ws[NTM * 16];
    const int bid = blockIdx.x;
    const int g = bid >> 5, r = bid & 31;
    const int c = g * 8 + (r & 7), bg = r >> 3;
    const int tid = threadIdx.x;
    for (int idx = tid; idx < 16 * NTM; idx += 256) {
        int bl = idx / NTM, tm = idx - bl * NTM;
        ws[tm * 16 + bl] = wbuf[((size_t)((bg * 16 + bl) * NCLS + c)) * NTM + tm];
    }
    __syncthreads();
    float a0[16] = {}, a1[16] = {};
    const unsigned int* vrow = (const unsigned int*)(tfeb + (size_t)c * NTM * DIM) + tid;
    #pragma unroll 4
    for (int tm = 0; tm < NTM; tm++) {
        unsigned int u = vrow[tm * 256];
        float vx = __uint_as_float(u << 16);
        float vy = __uint_as_float(u & 0xFFFF0000u);
        float wq[16];
        *(float4*)(wq + 0)  = *(const float4*)(ws + tm * 16 + 0);
        *(float4*)(wq + 4)  = *(const float4*)(ws + tm * 16 + 4);
        *(float4*)(wq + 8)  = *(const float4*)(ws + tm * 16 + 8);
        *(float4*)(wq + 12) = *(const float4*)(ws + tm * 16 + 12);
        #pragma unroll
        for (int bl = 0; bl < 16; bl++) {
            a0[bl] += wq[bl] * vx; a1[bl] += wq[bl] * vy;
        }
    }
    #pragma unroll
    for (int bl = 0; bl < 16; bl++) {
        int b = bg * 16 + bl;
        unsigned int o = (unsigned int)f2bf(a0[bl]) | ((unsigned int)f2bf(a1[bl]) << 16);
        ((unsigned int*)ctxraw)[(size_t)(b * NCLS + c) * 256 + tid] = o;
    }
}

// ---------- n2[b,d] = sum_c txt[b,c,d]^2 ----------
__global__ __launch_bounds__(256)
void n2_kernel(const unsigned short* __restrict__ txt, float* __restrict__ n2)
{
    const int b = blockIdx.x, cg = blockIdx.y, t = threadIdx.x;
    float a0 = 0.f, a1 = 0.f;
    const unsigned int* p = (const unsigned int*)txt + ((size_t)(b * NCLS + cg * 125)) * 256 + t;
    for (int c = 0; c < 125; c++) {
        unsigned int u = p[c * 256];
        float vx = __uint_as_float(u << 16);
        float vy = __uint_as_float(u & 0xFFFF0000u);
        a0 += vx * vx; a1 += vy * vy;
    }
    atomicAdd(&n2[b * DIM + t * 2], a0);
    atomicAdd(&n2[b * DIM + t * 2 + 1], a1);
}

// ---------- logits[b,c] = exp(ls) * sum_d imgn[b,d]/sqrt(n2[b,d]) * txt[b,c,d] ----------
__global__ __launch_bounds__(256)
void logits_kernel(const unsigned short* __restrict__ txt, const float* __restrict__ imgn,
                   const float* __restrict__ n2, const float* __restrict__ logit_scale,
                   float* __restrict__ out)
{
    __shared__ float lu[DIM];
    const int b = blockIdx.y, cg = blockIdx.x, tid = threadIdx.x;
    float els = expf(logit_scale[0]);
    lu[tid]       = els * imgn[b*DIM + tid]       * rsqrtf(n2[b*DIM + tid]);
    lu[tid + 256] = els * imgn[b*DIM + tid + 256] * rsqrtf(n2[b*DIM + tid + 256]);
    __syncthreads();
    int wave = tid >> 6, lane = tid & 63;
    int c = (cg << 2) + wave;
    const unsigned short* row = txt + (size_t)(b * NCLS + c) * DIM;
    ushort4 p0 = ((const ushort4*)row)[lane*2];
    ushort4 p1 = ((const ushort4*)row)[lane*2 + 1];
    int d0 = lane * 8;
    float s = bf2f(p0.x)*lu[d0]   + bf2f(p0.y)*lu[d0+1] + bf2f(p0.z)*lu[d0+2] + bf2f(p0.w)*lu[d0+3]
            + bf2f(p1.x)*lu[d0+4] + bf2f(p1.y)*lu[d0+5] + bf2f(p1.z)*lu[d0+6] + bf2f(p1.w)*lu[d0+7];
    #pragma unroll
    for (int off = 32; off > 0; off >>= 1) s += __shfl_down(s, off, 64);
    if (lane == 0) out[b*NCLS + c] = s;
}

extern "C" void kernel_launch(void* const* d_in, const int* in_sizes, int n_in,
                              void* d_out, int out_size, void* d_ws, size_t ws_size,
                              hipStream_t stream)
{
    const float* x   = (const float*)d_in[0];
    const float* tfe = (const float*)d_in[1];
    const float* siw = (const float*)d_in[2];
    const float* sib = (const float*)d_in[3];
    const float* sow = (const float*)d_in[4];
    const float* sob = (const float*)d_in[5];
    const float* ciw = (const float*)d_in[6];
    const float* cib = (const float*)d_in[7];
    const float* cow = (const float*)d_in[8];
    const float* cob = (const float*)d_in[9];
    const float* ls  = (const float*)d_in[10];
    float* out = (float*)d_out;

    char* p = (char*)d_ws;
    auto alloc = [&](size_t bytes) { char* r = p; p += (bytes + 255) & ~255ull; return r; };
    unsigned short* tfeb   = (unsigned short*)alloc((size_t)49152000 * 2);   // 98.3 MB
    unsigned short* ctxraw = (unsigned short*)alloc((size_t)BATCH * NCLS * DIM * 2);  // 65.5 MB
    float* wbuf            = (float*)alloc((size_t)BATCH * NCLS * NTM * 4);  // 24.6 MB
    float* qkv             = (float*)alloc((size_t)768 * 1536 * 4);
    float* ao              = (float*)alloc((size_t)768 * DIM * 4);
    float* xs              = (float*)alloc((size_t)768 * DIM * 4);
    float* q2s             = (float*)alloc((size_t)768 * DIM * 4);
    float* q2k             = (float*)alloc((size_t)768 * DIM * 4);
    unsigned short* q2pb   = (unsigned short*)alloc((size_t)1024 * DIM * 2);
    unsigned short* Wvob   = (unsigned short*)alloc((size_t)DIM * DIM * 2);
    float* bvo             = (float*)alloc(DIM * 4);
    float* n2              = (float*)alloc(BATCH * DIM * 4);
    float* imgn            = (float*)alloc(BATCH * DIM * 4);
    unsigned short* txt    = tfeb;   // alias: tfeb dead after ctx_kernel; txt written after

    hipMemsetAsync(n2, 0, BATCH * DIM * 4, stream);

    // weight/text prep
    f2bf_kernel<<<48000, 256, 0, stream>>>(tfe, tfeb, 49152000);
    fold_wvo<<<512, 256, 0, stream>>>(cow, ciw + 1024*512, cib + 1024, cob, Wvob, bvo);

    // self-attn head (fp32, small)
    gemm_bt_f32<<<dim3(24, 12), 256, 0, stream>>>(x, siw, sib, qkv, 768, 1536, 512, 1.f);
    attn_kernel<<<64, 256, 0, stream>>>(qkv, ao);
    gemm_bt_f32<<<dim3(8, 12), 256, 0, stream>>>(ao, sow, sob, xs, 768, 512, 512, 1.f);
    img_kernel<<<64, 256, 0, stream>>>(xs, imgn);
    gemm_bt_f32<<<dim3(8, 12), 256, 0, stream>>>(xs, ciw, cib, q2s, 768, 512, 512, SCALEF);
    // fold cWk into query: q2k = q2s @ cWk   (k-bias cancels in softmax over m)
    gemm_nt_f32<<<dim3(8, 12), 256, 0, stream>>>(q2s, ciw + 512*512, q2k, 768, 512, 512);
    build_q2p<<<dim3(16, 64), 256, 0, stream>>>(q2k, q2pb);

    // fused scores+softmax -> w[b,c,96]  (K = raw text features; XCD-grouped 1-D grid)
    fused_scores<<<4000, 256, 0, stream>>>(q2pb, tfeb, wbuf);

    // ctxraw = w @ tf  (value projection deferred past the template/layer average)
    ctx_kernel<<<4000, 256, 0, stream>>>(wbuf, tfeb, ctxraw);

    // txt = ctxraw @ Wvob^T + (bvo + cob)   (MFMA, 64000 rows)
    gemm_mfma<unsigned short><<<dim3(4, 500), 256, 0, stream>>>(
        ctxraw, Wvob, bvo, txt, 64000, 512, 1.f);

    // norms and logits
    n2_kernel<<<dim3(64, 8), 256, 0, stream>>>(txt, n2);
    logits_kernel<<<dim3(250, 64), 256, 0, stream>>>(txt, imgn, n2, ls, out);
}